// Round 5
// baseline (163.264 us; speedup 1.0000x reference)
//
#include <hip/hip_runtime.h>
#include <math.h>

#define KNN 16
#define NPTS 8192
#define PTCH 256
#define NPATCH 32
#define NBATCH 4
#define NQ 32            // queries per block (eighth patch)
#define SSTRIDE 130      // survivor slots/query (mean 64, +8sigma)
#define LAMBDA_T 64.0f   // target E[survivors]/query

// spatial grid
#define NC 16
#define NCELLS (NC * NC * NC)
#define GMIN -4.2f
#define ICS 1.9047619f   // 1 / 0.525 ; NC*0.525 = 8.4 spans [-4.2, 4.2]

// E[#points within distance s of a query at radius r], N iid N(0,I3). fp32.
// Heuristic only: exactness guaranteed by phase-B margin check + fallback.
__device__ __forceinline__ float lam_f(float r, float s)
{
    const float C     = 0.063493636f;    // (2*pi)^{-3/2}
    const float SQ2PI = 2.5066283f;
    const float IS2   = 0.70710678f;
    float a = fabsf(r - s), b = r + s;
    float amr = a - r;
    float coefA = amr * amr + 2.f - s * s;
    float I = 2.f * __expf(-0.5f * b * b) - coefA * __expf(-0.5f * a * a)
            + r * SQ2PI * (erff(b * IS2) - erff(a * IS2));
    float M = C * (3.14159265f / r) * I;
    if (s > r) {
        float u = s - r;
        M += 12.566371f * C * (1.2533141f * erff(u * IS2) - u * __expf(-0.5f * u * u));
    }
    return (float)NPTS * M;
}

// ---------- fp64 cyclic Jacobi 3x3 (verified R1-R7) ----------
__device__ __forceinline__ void jrot(double& app, double& aqq, double& apq,
                                     double& arp, double& arq,
                                     double& vp0, double& vq0,
                                     double& vp1, double& vq1,
                                     double& vp2, double& vq2)
{
    double g = apq;
    if (g == 0.0) return;
    double theta = (aqq - app) / (2.0 * g);
    double at = fabs(theta);
    double t = (at > 1.0e154) ? (0.5 / theta)
                              : (copysign(1.0, theta) / (at + sqrt(theta * theta + 1.0)));
    double c = 1.0 / sqrt(t * t + 1.0);
    double s = t * c;
    double tau = s / (1.0 + c);
    app -= t * g;
    aqq += t * g;
    apq = 0.0;
    double rp = arp, rq = arq;
    arp = rp - s * (rq + tau * rp);
    arq = rq + s * (rp - tau * rq);
    double p0 = vp0, q0 = vq0;
    vp0 = p0 - s * (q0 + tau * p0); vq0 = q0 + s * (p0 - tau * q0);
    double p1 = vp1, q1 = vq1;
    vp1 = p1 - s * (q1 + tau * p1); vq1 = q1 + s * (p1 - tau * q1);
    double p2 = vp2, q2 = vq2;
    vp2 = p2 - s * (q2 + tau * p2); vq2 = q2 + s * (p2 - tau * q2);
}

__device__ __forceinline__ void eig3(double a00, double a11, double a22,
                                     double a01, double a02, double a12,
                                     double& nx, double& ny, double& nz,
                                     double& lmin, double& lsum)
{
    double v00 = 1, v01 = 0, v02 = 0;
    double v10 = 0, v11 = 1, v12 = 0;
    double v20 = 0, v21 = 0, v22 = 1;
    double scale = fabs(a00) + fabs(a11) + fabs(a22) + fabs(a01) + fabs(a02) + fabs(a12);
    if (scale > 0.0) {
        for (int sweep = 0; sweep < 6; ++sweep) {
            double off = fabs(a01) + fabs(a02) + fabs(a12);
            if (off <= scale * 1e-15) break;
            jrot(a00, a11, a01, a02, a12, v00, v01, v10, v11, v20, v21);
            jrot(a00, a22, a02, a01, a12, v00, v02, v10, v12, v20, v22);
            jrot(a11, a22, a12, a01, a02, v01, v02, v11, v12, v21, v22);
        }
    }
    lsum = a00 + a11 + a22;
    lmin = a00; nx = v00; ny = v10; nz = v20;
    if (a11 < lmin) { lmin = a11; nx = v01; ny = v11; nz = v21; }
    if (a22 < lmin) { lmin = a22; nx = v02; ny = v12; nz = v22; }
}

// u32 key: (d2 float bits, low 13 mantissa bits cleared) | idx(13b). Ties -> lower idx.
__device__ __forceinline__ unsigned mkkey(float d2, unsigned idx) {
    return (__float_as_uint(d2) & 0xFFFFE000u) | idx;
}

// Caller guarantees key < L[15]. Sorted-ascending bubble (v_min/v_max pairs).
__device__ __forceinline__ void insert16(unsigned key, unsigned* L)
{
    L[KNN - 1] = key;
    #pragma unroll
    for (int m = KNN - 1; m >= 1; --m) {
        unsigned a = L[m - 1], b = L[m];
        L[m - 1] = min(a, b);
        L[m]     = max(a, b);
    }
}

// Snapshot-based butterfly merge of sorted 16-lists across lanes h = lane&3.
__device__ __forceinline__ void merge4(unsigned* L, int lane)
{
    #pragma unroll
    for (int step = 1; step <= 2; step <<= 1) {
        unsigned tmp[KNN];
        #pragma unroll
        for (int m = 0; m < KNN; ++m) tmp[m] = __shfl(L[m], lane ^ step, 64);
        for (int m = 0; m < KNN; ++m) {
            if (tmp[m] >= L[KNN - 1]) break;
            insert16(tmp[m], L);
        }
    }
}

__device__ __forceinline__ float rfl(float x) {
    return __int_as_float(__builtin_amdgcn_readfirstlane(__float_as_int(x)));
}
__device__ __forceinline__ unsigned mbcnt64(unsigned long long m) {
    return __builtin_amdgcn_mbcnt_hi((unsigned)(m >> 32),
           __builtin_amdgcn_mbcnt_lo((unsigned)m, 0u));
}

// ---------- grid build ----------
__device__ __forceinline__ int cidx(float v) {
    int i = (int)floorf((v - GMIN) * ICS);
    return min(max(i, 0), NC - 1);
}
__device__ __forceinline__ int cellOf(float x, float y, float z) {
    return (cidx(z) * NC + cidx(y)) * NC + cidx(x);
}

// One block per batch: zero out + histogram + scan + scatter, all in LDS.
#define BT 1024
__global__ void __launch_bounds__(1024)
build_kernel(const float* __restrict__ pts, float* __restrict__ out,
             unsigned* __restrict__ cellStart, float4* __restrict__ sorted)
{
    __shared__ unsigned hist[NCELLS];     // 16 KB; reused as cellPos after scan
    __shared__ unsigned part[BT];         // 4 KB
    const int b = blockIdx.x;
    const int t = threadIdx.x;
    if (b == 0 && t == 0) { out[0] = 0.0f; out[1] = 0.0f; }
    for (int i = t; i < NCELLS; i += BT) hist[i] = 0u;
    __syncthreads();
    const float* base = pts + (size_t)b * (NPTS * 3);
    float px[8], py[8], pz[8];
    int pc[8];
    #pragma unroll
    for (int k = 0; k < 8; ++k) {
        int i = k * BT + t;
        px[k] = base[i * 3 + 0];
        py[k] = base[i * 3 + 1];
        pz[k] = base[i * 3 + 2];
        pc[k] = cellOf(px[k], py[k], pz[k]);
        atomicAdd(&hist[pc[k]], 1u);
    }
    __syncthreads();
    // scan: thread t owns cells t*4 .. t*4+3
    unsigned loc[4], s = 0;
    #pragma unroll
    for (int i = 0; i < 4; ++i) { loc[i] = s; s += hist[t * 4 + i]; }
    part[t] = s;
    __syncthreads();
    for (int o = 1; o < BT; o <<= 1) {
        unsigned u = (t >= o) ? part[t - o] : 0u;
        __syncthreads();
        part[t] += u;
        __syncthreads();
    }
    unsigned basex = part[t] - s;   // exclusive prefix of this thread's 4-cell chunk
    unsigned* csb = cellStart + b * (NCELLS + 1);
    #pragma unroll
    for (int i = 0; i < 4; ++i) {
        unsigned e = basex + loc[i];
        csb[t * 4 + i] = e;
        hist[t * 4 + i] = e;        // becomes running cell position
    }
    if (t == BT - 1) csb[NCELLS] = basex + s;   // == NPTS
    __syncthreads();
    float4* sb = sorted + (size_t)b * NPTS;
    #pragma unroll
    for (int k = 0; k < 8; ++k) {
        int i = k * BT + t;
        unsigned slot = atomicAdd(&hist[pc[k]], 1u);
        float4 v;
        v.x = px[k]; v.y = py[k]; v.z = pz[k]; v.w = __uint_as_float((unsigned)i);
        sb[slot] = v;
    }
}

// Block = 256 threads, 32 queries (eighth patch); grid 1024.
// Phase A (R5): static row x slot lane mapping. Per iteration: R rows x
//   SL=64/R slots (R adapted to the query's row count). Row bounds preloaded
//   per 64 rows (packed start|len<<14); per group ONE bpermute fetches my
//   row's bounds, then lanes stream sorted[] with locally-computed addresses.
//   Replaces R4's 6-dependent-bpermute binary search per chunk (the measured
//   latency wall: ~700-1200 cy of LDS latency per 64 candidates).
// Phase B: waves0/1 = global top-16 (4 lanes/query); waves2/3 = patch kNN.
__global__ void __launch_bounds__(256, 4)
spl_main(const float* __restrict__ pts, float* __restrict__ out,
         const unsigned* __restrict__ cellStart, const float4* __restrict__ sortedp)
{
    __shared__ float4 pbuf4[PTCH];                 // 4 KB own patch
    __shared__ unsigned survk[NQ * SSTRIDE];       // 16.6 KB survivor keys
    __shared__ unsigned cnts[NQ];
    __shared__ float gbuf[NQ];                     // gates (g^2)
    __shared__ double xbuf[NQ * 4];                // patch normal+sv
    __shared__ double rb[4];                       // partials
    // ~22 KB

    const int t = threadIdx.x;
    const int w = t >> 6;
    const int lane = t & 63;
    const int p = blockIdx.x;
    const int eighth = blockIdx.y;
    const int b = blockIdx.z;

    const float* base = pts + (size_t)b * (NPTS * 3);
    const int qbase = p * PTCH + eighth * NQ;
    const unsigned* cs = cellStart + b * (NCELLS + 1);
    const float4* sp = sortedp + (size_t)b * NPTS;

    // Stage own patch into padded LDS.
    {
        const float* src = base + p * (PTCH * 3);
        float* dst = (float*)pbuf4;
        #pragma unroll
        for (int s = 0; s < 3; ++s) {
            int f = t + s * 256;
            int j = f / 3;
            int c = f - 3 * j;
            dst[j * 4 + c] = src[f];
        }
    }
    // Gates for this block's 32 queries (fp32 bisection, threads 0..31).
    if (t < NQ) {
        int qi = qbase + t;
        float x = base[qi * 3 + 0], y = base[qi * 3 + 1], z = base[qi * 3 + 2];
        float r = fmaxf(sqrtf(x * x + y * y + z * z), 0.01f);
        float lo = 0.f, hi = 12.f;
        #pragma unroll 1
        for (int it = 0; it < 16; ++it) {
            float mid = 0.5f * (lo + hi);
            if (lam_f(r, mid) < LAMBDA_T) lo = mid; else hi = mid;
        }
        gbuf[t] = hi * hi;
    }
    __syncthreads();

    // ---- Phase A: grid-gated filter, 8 serial queries per wave ----
    #pragma unroll 1
    for (int u = 0; u < 8; ++u) {
        const int q = w * 8 + u;
        float4 qv = pbuf4[eighth * NQ + q];
        float qx = rfl(qv.x), qy = rfl(qv.y), qz = rfl(qv.z);
        float g2 = rfl(gbuf[q]);
        float g = sqrtf(g2);
        int ixlo = cidx(qx - g), ixhi = cidx(qx + g);
        int iylo = cidx(qy - g), iyhi = cidx(qy + g);
        int izlo = cidx(qz - g), izhi = cidx(qz + g);
        int nx = ixhi - ixlo + 1;
        int ny = iyhi - iylo + 1;
        int nyz = ny * (izhi - izlo + 1);
        // rows per group R (pow2 <= 8, adapted), slots per row SL = 64/R
        const int lR  = (nyz >= 8) ? 3 : (nyz >= 4) ? 2 : (nyz >= 2) ? 1 : 0;
        const int R   = 1 << lR;
        const int lsl = 6 - lR;
        const unsigned SL = 64u >> lR;
        const unsigned slot = (unsigned)lane & (SL - 1u);
        unsigned cnt = 0;                          // wave-uniform by construction
        unsigned sbase = (unsigned)q * SSTRIDE;
        #pragma unroll 1
        for (int r0 = 0; r0 < nyz; r0 += 64) {
            // lane r owns one cell-row (nx contiguous cells): packed start|len<<14
            int r = r0 + lane;
            unsigned pk = 0;
            if (r < nyz) {
                int iz = izlo + r / ny;
                int iy = iylo + (r - (r / ny) * ny);
                int cb = (iz * NC + iy) * NC + ixlo;
                unsigned sB = cs[cb];
                pk = sB | ((cs[cb + nx] - sB) << 14);
            }
            int rmax = min(nyz - r0, 64);
            int gcount = (rmax + R - 1) >> lR;
            #pragma unroll 1
            for (int gg = 0; gg < gcount; ++gg) {
                unsigned pkm = __shfl(pk, (gg << lR) + (lane >> lsl), 64);
                unsigned sBm = pkm & 0x3FFFu;
                unsigned lm  = pkm >> 14;
                #pragma unroll 1
                for (unsigned st = slot; ; st += SL) {
                    bool in = st < lm;
                    if (!__any(in ? 1 : 0)) break;
                    float4 c = sp[min(sBm + st, (unsigned)(NPTS - 1))];
                    float dx = qx - c.x, dy = qy - c.y, dz = qz - c.z;
                    float d2 = dx * dx + dy * dy + dz * dz;   // reference-form d2
                    bool pass = in && (d2 < g2);
                    unsigned long long m = __ballot(pass);
                    if (pass) {
                        unsigned sw = min(cnt + mbcnt64(m), (unsigned)(SSTRIDE - 1));
                        survk[sbase + sw] = mkkey(d2, __float_as_uint(c.w));
                    }
                    cnt += (unsigned)__popcll(m);
                }
            }
        }
        if (lane == 0) cnts[q] = cnt;
    }
    __syncthreads();   // B1

    // ---- Phase B: 4 lanes per query ----
    const int qq = lane >> 2;            // query within half 0..15
    const int h = lane & 3;              // sub-lane
    const int myq = (w & 1) * 16 + qq;   // query 0..31
    float4 qv = pbuf4[eighth * NQ + myq];
    const float pqx = qv.x, pqy = qv.y, pqz = qv.z;

    double ngx = 0, ngy = 0, ngz = 0, svg = 0;

    if (w < 2) {
        // Global top-16: split survivor keys 4 ways, gated bubble, butterfly merge.
        unsigned gl[KNN];
        #pragma unroll
        for (int m = 0; m < KNN; ++m) gl[m] = 0xFFFFFFFFu;
        unsigned cnt = cnts[myq];
        bool valid = (cnt >= KNN) && (cnt <= SSTRIDE);
        if (valid) {
            unsigned share = (cnt + 3) >> 2;
            unsigned m0 = h * share;
            unsigned m1 = min(m0 + share, cnt);
            #pragma unroll 1
            for (unsigned m = m0; m < m1; ++m) {
                unsigned k = survk[myq * SSTRIDE + m];
                if (k < gl[KNN - 1]) insert16(k, gl);
            }
        }
        merge4(gl, lane);
        if (valid) {
            // margin check: all filtered-out points provably outside 16th bucket
            float g = gbuf[myq];
            float upper = __uint_as_float((gl[KNN - 1] & 0xFFFFE000u) + 0x2000u);
            valid = (upper < g * 0.999f - 1e-5f);
        }
        if (__any((h == 0 && !valid) ? 1 : 0)) {
            if (h == 0 && !valid) {   // exact fallback (P ~ 1e-9/query)
                #pragma unroll
                for (int m = 0; m < KNN; ++m) gl[m] = 0xFFFFFFFFu;
                #pragma unroll 1
                for (int i = 0; i < NPTS; ++i) {
                    float cx = base[i * 3 + 0];
                    float cy = base[i * 3 + 1];
                    float cz = base[i * 3 + 2];
                    float dx = pqx - cx, dy = pqy - cy, dz = pqz - cz;
                    float d2 = dx * dx + dy * dy + dz * dz;
                    unsigned k = mkkey(d2, (unsigned)i);
                    if (k < gl[KNN - 1]) insert16(k, gl);
                }
            }
        }
        if (h == 0) {
            double c00 = 0, c11 = 0, c22 = 0, c01 = 0, c02 = 0, c12 = 0;
            const double qxd = pqx, qyd = pqy, qzd = pqz;
            #pragma unroll
            for (int m = 0; m < KNN; ++m) {
                int idx = (int)(gl[m] & 0x1FFFu);
                double dx = (double)base[idx * 3 + 0] - qxd;
                double dy = (double)base[idx * 3 + 1] - qyd;
                double dz = (double)base[idx * 3 + 2] - qzd;
                c00 += dx * dx; c11 += dy * dy; c22 += dz * dz;
                c01 += dx * dy; c02 += dx * dz; c12 += dy * dz;
            }
            double lmin, lsum;
            eig3(c00, c11, c22, c01, c02, c12, ngx, ngy, ngz, lmin, lsum);
            svg = lmin / lsum;
        }
    } else {
        // Patch kNN: 4 lanes x 64 patch points, gated bubble, butterfly merge.
        unsigned pl[KNN];
        #pragma unroll
        for (int m = 0; m < KNN; ++m) pl[m] = 0xFFFFFFFFu;
        const int j0 = h * 64;
        #pragma unroll 1
        for (int j = j0; j < j0 + 64; ++j) {
            float4 c = pbuf4[j];
            float dx = pqx - c.x, dy = pqy - c.y, dz = pqz - c.z;
            float d2 = dx * dx + dy * dy + dz * dz;
            unsigned k = mkkey(d2, (unsigned)j);
            if (k < pl[KNN - 1]) insert16(k, pl);
        }
        merge4(pl, lane);
        if (h == 0) {
            double c00 = 0, c11 = 0, c22 = 0, c01 = 0, c02 = 0, c12 = 0;
            const double qxd = pqx, qyd = pqy, qzd = pqz;
            #pragma unroll
            for (int m = 0; m < KNN; ++m) {
                int idx = (int)(pl[m] & 0x1FFFu);
                float4 cpt = pbuf4[idx];
                double dx = (double)cpt.x - qxd;
                double dy = (double)cpt.y - qyd;
                double dz = (double)cpt.z - qzd;
                c00 += dx * dx; c11 += dy * dy; c22 += dz * dz;
                c01 += dx * dy; c02 += dx * dz; c12 += dy * dz;
            }
            double nx, ny, nz, lmin, lsum;
            eig3(c00, c11, c22, c01, c02, c12, nx, ny, nz, lmin, lsum);
            xbuf[myq * 4 + 0] = nx;
            xbuf[myq * 4 + 1] = ny;
            xbuf[myq * 4 + 2] = nz;
            xbuf[myq * 4 + 3] = lmin / lsum;
        }
    }
    __syncthreads();   // B2

    double ln = 0.0, lsv = 0.0;
    if (w < 2 && h == 0) {
        double npx = xbuf[myq * 4 + 0];
        double npy = xbuf[myq * 4 + 1];
        double npz = xbuf[myq * 4 + 2];
        double svp = xbuf[myq * 4 + 3];
        double dx = fabs(npx) - fabs(ngx);
        double dy = fabs(npy) - fabs(ngy);
        double dz = fabs(npz) - fabs(ngz);
        ln  = sqrt(dx * dx + dy * dy + dz * dz);
        double ds = svp - svg;
        lsv = ds * ds;
    }
    if (w < 2) {
        #pragma unroll
        for (int o = 32; o > 0; o >>= 1) {
            ln  += __shfl_down(ln, o);
            lsv += __shfl_down(lsv, o);
        }
        if (lane == 0) { rb[w * 2 + 0] = ln; rb[w * 2 + 1] = lsv; }
    }
    __syncthreads();   // B3
    if (t == 0) {
        const double inv = 1.0 / (double)(NBATCH * NPTS);
        atomicAdd(&out[0], (float)((rb[0] + rb[2]) * inv));
        atomicAdd(&out[1], (float)((rb[1] + rb[3]) * inv));
    }
}

extern "C" void kernel_launch(void* const* d_in, const int* in_sizes, int n_in,
                              void* d_out, int out_size, void* d_ws, size_t ws_size,
                              hipStream_t stream)
{
    const float* pts = (const float*)d_in[0];
    float* out = (float*)d_out;

    // workspace carve-up (16B-aligned): ~590 KB total
    unsigned char* ws = (unsigned char*)d_ws;
    unsigned* cellStart = (unsigned*)(ws);            // 4*4097*4 = 65552 B
    float4*   sorted    = (float4*)  (ws + 65552);    // 4*8192*16 = 524288 B

    hipLaunchKernelGGL(build_kernel, dim3(NBATCH), dim3(BT), 0, stream,
                       pts, out, cellStart, sorted);
    dim3 grid(NPATCH, 8, NBATCH);
    hipLaunchKernelGGL(spl_main, grid, dim3(256), 0, stream, pts, out, cellStart, sorted);
}

// Round 6
// 162.075 us; speedup vs baseline: 1.0073x; 1.0073x over previous
//
#include <hip/hip_runtime.h>
#include <math.h>

#define KNN 16
#define NPTS 8192
#define PTCH 256
#define NPATCH 32
#define NBATCH 4
#define NQ 32            // queries per select-block (eighth patch)
#define SSTRIDE 130      // survivor slots/query (mean 64, +8sigma)
#define LAMBDA_T 64.0f   // target E[survivors]/query

// spatial grid
#define NC 16
#define NCELLS (NC * NC * NC)
#define GMIN -4.2f
#define ICS 1.9047619f   // 1 / 0.525 ; NC*0.525 = 8.4 spans [-4.2, 4.2]

// E[#points within distance s of a query at radius r], N iid N(0,I3). fp32.
// Heuristic only: exactness guaranteed by select-phase margin check + fallback.
__device__ __forceinline__ float lam_f(float r, float s)
{
    const float C     = 0.063493636f;    // (2*pi)^{-3/2}
    const float SQ2PI = 2.5066283f;
    const float IS2   = 0.70710678f;
    float a = fabsf(r - s), b = r + s;
    float amr = a - r;
    float coefA = amr * amr + 2.f - s * s;
    float I = 2.f * __expf(-0.5f * b * b) - coefA * __expf(-0.5f * a * a)
            + r * SQ2PI * (erff(b * IS2) - erff(a * IS2));
    float M = C * (3.14159265f / r) * I;
    if (s > r) {
        float u = s - r;
        M += 12.566371f * C * (1.2533141f * erff(u * IS2) - u * __expf(-0.5f * u * u));
    }
    return (float)NPTS * M;
}

// ---------- fp64 cyclic Jacobi 3x3 (verified) ----------
__device__ __forceinline__ void jrot(double& app, double& aqq, double& apq,
                                     double& arp, double& arq,
                                     double& vp0, double& vq0,
                                     double& vp1, double& vq1,
                                     double& vp2, double& vq2)
{
    double g = apq;
    if (g == 0.0) return;
    double theta = (aqq - app) / (2.0 * g);
    double at = fabs(theta);
    double t = (at > 1.0e154) ? (0.5 / theta)
                              : (copysign(1.0, theta) / (at + sqrt(theta * theta + 1.0)));
    double c = 1.0 / sqrt(t * t + 1.0);
    double s = t * c;
    double tau = s / (1.0 + c);
    app -= t * g;
    aqq += t * g;
    apq = 0.0;
    double rp = arp, rq = arq;
    arp = rp - s * (rq + tau * rp);
    arq = rq + s * (rp - tau * rq);
    double p0 = vp0, q0 = vq0;
    vp0 = p0 - s * (q0 + tau * p0); vq0 = q0 + s * (p0 - tau * q0);
    double p1 = vp1, q1 = vq1;
    vp1 = p1 - s * (q1 + tau * p1); vq1 = q1 + s * (p1 - tau * q1);
    double p2 = vp2, q2 = vq2;
    vp2 = p2 - s * (q2 + tau * p2); vq2 = q2 + s * (p2 - tau * q2);
}

__device__ __forceinline__ void eig3(double a00, double a11, double a22,
                                     double a01, double a02, double a12,
                                     double& nx, double& ny, double& nz,
                                     double& lmin, double& lsum)
{
    double v00 = 1, v01 = 0, v02 = 0;
    double v10 = 0, v11 = 1, v12 = 0;
    double v20 = 0, v21 = 0, v22 = 1;
    double scale = fabs(a00) + fabs(a11) + fabs(a22) + fabs(a01) + fabs(a02) + fabs(a12);
    if (scale > 0.0) {
        for (int sweep = 0; sweep < 6; ++sweep) {
            double off = fabs(a01) + fabs(a02) + fabs(a12);
            if (off <= scale * 1e-15) break;
            jrot(a00, a11, a01, a02, a12, v00, v01, v10, v11, v20, v21);
            jrot(a00, a22, a02, a01, a12, v00, v02, v10, v12, v20, v22);
            jrot(a11, a22, a12, a01, a02, v01, v02, v11, v12, v21, v22);
        }
    }
    lsum = a00 + a11 + a22;
    lmin = a00; nx = v00; ny = v10; nz = v20;
    if (a11 < lmin) { lmin = a11; nx = v01; ny = v11; nz = v21; }
    if (a22 < lmin) { lmin = a22; nx = v02; ny = v12; nz = v22; }
}

// u32 key: (d2 float bits, low 13 mantissa bits cleared) | idx(13b). Ties -> lower idx.
__device__ __forceinline__ unsigned mkkey(float d2, unsigned idx) {
    return (__float_as_uint(d2) & 0xFFFFE000u) | idx;
}

// Caller guarantees key < L[15]. Sorted-ascending bubble (v_min/v_max pairs).
__device__ __forceinline__ void insert16(unsigned key, unsigned* L)
{
    L[KNN - 1] = key;
    #pragma unroll
    for (int m = KNN - 1; m >= 1; --m) {
        unsigned a = L[m - 1], b = L[m];
        L[m - 1] = min(a, b);
        L[m]     = max(a, b);
    }
}

// Snapshot-based butterfly merge of sorted 16-lists across lanes h = lane&3.
__device__ __forceinline__ void merge4(unsigned* L, int lane)
{
    #pragma unroll
    for (int step = 1; step <= 2; step <<= 1) {
        unsigned tmp[KNN];
        #pragma unroll
        for (int m = 0; m < KNN; ++m) tmp[m] = __shfl(L[m], lane ^ step, 64);
        for (int m = 0; m < KNN; ++m) {
            if (tmp[m] >= L[KNN - 1]) break;
            insert16(tmp[m], L);
        }
    }
}

__device__ __forceinline__ float rfl(float x) {
    return __int_as_float(__builtin_amdgcn_readfirstlane(__float_as_int(x)));
}
__device__ __forceinline__ unsigned mbcnt64(unsigned long long m) {
    return __builtin_amdgcn_mbcnt_hi((unsigned)(m >> 32),
           __builtin_amdgcn_mbcnt_lo((unsigned)m, 0u));
}

// ---------- grid build ----------
__device__ __forceinline__ int cidx(float v) {
    int i = (int)floorf((v - GMIN) * ICS);
    return min(max(i, 0), NC - 1);
}
__device__ __forceinline__ int cellOf(float x, float y, float z) {
    return (cidx(z) * NC + cidx(y)) * NC + cidx(x);
}

// One block per batch: zero out + histogram + scan + scatter, all in LDS.
#define BT 1024
__global__ void __launch_bounds__(1024)
build_kernel(const float* __restrict__ pts, float* __restrict__ out,
             unsigned* __restrict__ cellStart, float4* __restrict__ sorted)
{
    __shared__ unsigned hist[NCELLS];     // 16 KB; reused as cellPos after scan
    __shared__ unsigned part[BT];         // 4 KB
    const int b = blockIdx.x;
    const int t = threadIdx.x;
    if (b == 0 && t == 0) { out[0] = 0.0f; out[1] = 0.0f; }
    for (int i = t; i < NCELLS; i += BT) hist[i] = 0u;
    __syncthreads();
    const float* base = pts + (size_t)b * (NPTS * 3);
    float px[8], py[8], pz[8];
    int pc[8];
    #pragma unroll
    for (int k = 0; k < 8; ++k) {
        int i = k * BT + t;
        px[k] = base[i * 3 + 0];
        py[k] = base[i * 3 + 1];
        pz[k] = base[i * 3 + 2];
        pc[k] = cellOf(px[k], py[k], pz[k]);
        atomicAdd(&hist[pc[k]], 1u);
    }
    __syncthreads();
    // scan: thread t owns cells t*4 .. t*4+3
    unsigned loc[4], s = 0;
    #pragma unroll
    for (int i = 0; i < 4; ++i) { loc[i] = s; s += hist[t * 4 + i]; }
    part[t] = s;
    __syncthreads();
    for (int o = 1; o < BT; o <<= 1) {
        unsigned u = (t >= o) ? part[t - o] : 0u;
        __syncthreads();
        part[t] += u;
        __syncthreads();
    }
    unsigned basex = part[t] - s;   // exclusive prefix of this thread's 4-cell chunk
    unsigned* csb = cellStart + b * (NCELLS + 1);
    #pragma unroll
    for (int i = 0; i < 4; ++i) {
        unsigned e = basex + loc[i];
        csb[t * 4 + i] = e;
        hist[t * 4 + i] = e;        // becomes running cell position
    }
    if (t == BT - 1) csb[NCELLS] = basex + s;   // == NPTS
    __syncthreads();
    float4* sb = sorted + (size_t)b * NPTS;
    #pragma unroll
    for (int k = 0; k < 8; ++k) {
        int i = k * BT + t;
        unsigned slot = atomicAdd(&hist[pc[k]], 1u);
        float4 v;
        v.x = px[k]; v.y = py[k]; v.z = pz[k]; v.w = __uint_as_float((unsigned)i);
        sb[slot] = v;
    }
}

// One THREAD per query: 32768 gate bisections fully SIMT-parallel.
// (Was: 32 threads per 256-block, serializing 7 waves behind a half-wave.)
__global__ void __launch_bounds__(256)
gate_kernel(const float* __restrict__ pts, float* __restrict__ g2buf)
{
    int q = blockIdx.x * 256 + threadIdx.x;     // 0..32767
    int b = q >> 13, i = q & (NPTS - 1);
    const float* pp = pts + (size_t)b * (NPTS * 3) + (size_t)i * 3;
    float x = pp[0], y = pp[1], z = pp[2];
    float r = fmaxf(sqrtf(x * x + y * y + z * z), 0.01f);
    float lo = 0.f, hi = 12.f;
    #pragma unroll 1
    for (int it = 0; it < 16; ++it) {
        float mid = 0.5f * (lo + hi);
        if (lam_f(r, mid) < LAMBDA_T) lo = mid; else hi = mid;
    }
    g2buf[q] = hi * hi;
}

// One WAVE per query (32768 waves): R5's verified row x slot streaming body,
// survivor keys to global. Per-wave chain = ONE query (~3k cy) instead of 8.
__global__ void __launch_bounds__(256)
filter_kernel(const float* __restrict__ pts, const float* __restrict__ g2buf,
              const unsigned* __restrict__ cellStart,
              const float4* __restrict__ sortedp,
              unsigned* __restrict__ survk, unsigned* __restrict__ cnts)
{
    const int lane = threadIdx.x & 63;
    const int wq = __builtin_amdgcn_readfirstlane(
        (int)((blockIdx.x * 256u + (unsigned)threadIdx.x) >> 6));  // query id
    const int b  = wq >> 13;
    const int qi = wq & (NPTS - 1);
    const float* base = pts + (size_t)b * (NPTS * 3);
    const unsigned* cs = cellStart + b * (NCELLS + 1);
    const float4* sp = sortedp + (size_t)b * NPTS;

    const float qx = base[qi * 3 + 0];   // wave-uniform scalar loads
    const float qy = base[qi * 3 + 1];
    const float qz = base[qi * 3 + 2];
    const float g2 = g2buf[wq];
    const float g  = sqrtf(g2);

    int ixlo = cidx(qx - g), ixhi = cidx(qx + g);
    int iylo = cidx(qy - g), iyhi = cidx(qy + g);
    int izlo = cidx(qz - g), izhi = cidx(qz + g);
    int nx = ixhi - ixlo + 1;
    int ny = iyhi - iylo + 1;
    int nyz = ny * (izhi - izlo + 1);
    const int lR  = (nyz >= 8) ? 3 : (nyz >= 4) ? 2 : (nyz >= 2) ? 1 : 0;
    const int R   = 1 << lR;
    const int lsl = 6 - lR;
    const unsigned SL = 64u >> lR;
    const unsigned slot = (unsigned)lane & (SL - 1u);
    unsigned cnt = 0;                          // wave-uniform by construction
    unsigned sbase = (unsigned)wq * SSTRIDE;
    #pragma unroll 1
    for (int r0 = 0; r0 < nyz; r0 += 64) {
        int r = r0 + lane;
        unsigned pk = 0;
        if (r < nyz) {
            int iz = izlo + r / ny;
            int iy = iylo + (r - (r / ny) * ny);
            int cb = (iz * NC + iy) * NC + ixlo;
            unsigned sB = cs[cb];
            pk = sB | ((cs[cb + nx] - sB) << 14);
        }
        int rmax = min(nyz - r0, 64);
        int gcount = (rmax + R - 1) >> lR;
        #pragma unroll 1
        for (int gg = 0; gg < gcount; ++gg) {
            unsigned pkm = __shfl(pk, (gg << lR) + (lane >> lsl), 64);
            unsigned sBm = pkm & 0x3FFFu;
            unsigned lm  = pkm >> 14;
            #pragma unroll 1
            for (unsigned st = slot; ; st += SL) {
                bool in = st < lm;
                if (!__any(in ? 1 : 0)) break;
                float4 c = sp[min(sBm + st, (unsigned)(NPTS - 1))];
                float dx = qx - c.x, dy = qy - c.y, dz = qz - c.z;
                float d2 = dx * dx + dy * dy + dz * dz;   // reference-form d2
                bool pass = in && (d2 < g2);
                unsigned long long m = __ballot(pass);
                if (pass) {
                    unsigned sw = min(cnt + mbcnt64(m), (unsigned)(SSTRIDE - 1));
                    survk[sbase + sw] = mkkey(d2, __float_as_uint(c.w));
                }
                cnt += (unsigned)__popcll(m);
            }
        }
    }
    if (lane == 0) cnts[wq] = cnt;
}

// Block = 256 threads, 32 queries; grid 1024. Phase B only: stage survivors
// (coalesced) + patch into LDS, then the verified select/eig/loss path.
__global__ void __launch_bounds__(256, 4)
select_kernel(const float* __restrict__ pts, float* __restrict__ out,
              const float* __restrict__ g2buf,
              const unsigned* __restrict__ survk_g,
              const unsigned* __restrict__ cnts_g)
{
    __shared__ float4 pbuf4[PTCH];                 // 4 KB own patch
    __shared__ unsigned survl[NQ * SSTRIDE];       // 16.6 KB survivor keys
    __shared__ unsigned cnts[NQ];
    __shared__ double xbuf[NQ * 4];                // patch normal+sv
    __shared__ double rb[4];                       // partials

    const int t = threadIdx.x;
    const int w = t >> 6;
    const int lane = t & 63;
    const int p = blockIdx.x;
    const int eighth = blockIdx.y;
    const int b = blockIdx.z;

    const float* base = pts + (size_t)b * (NPTS * 3);
    const int qbase = p * PTCH + eighth * NQ;
    const int qg0 = b * NPTS + qbase;              // block's first global query id

    // Stage own patch into padded LDS.
    {
        const float* src = base + p * (PTCH * 3);
        float* dst = (float*)pbuf4;
        #pragma unroll
        for (int s = 0; s < 3; ++s) {
            int f = t + s * 256;
            int j = f / 3;
            int c = f - 3 * j;
            dst[j * 4 + c] = src[f];
        }
    }
    // Stage survivors (fully coalesced rows) + counts.
    {
        const unsigned* src = survk_g + (size_t)qg0 * SSTRIDE;
        #pragma unroll 1
        for (int i = t; i < NQ * SSTRIDE; i += 256) survl[i] = src[i];
        if (t < NQ) cnts[t] = cnts_g[qg0 + t];
    }
    __syncthreads();

    // ---- 4 lanes per query ----
    const int qq = lane >> 2;            // query within half 0..15
    const int h = lane & 3;              // sub-lane
    const int myq = (w & 1) * 16 + qq;   // query 0..31
    float4 qv = pbuf4[eighth * NQ + myq];
    const float pqx = qv.x, pqy = qv.y, pqz = qv.z;

    double ngx = 0, ngy = 0, ngz = 0, svg = 0;

    if (w < 2) {
        // Global top-16: split survivor keys 4 ways, gated bubble, butterfly merge.
        unsigned gl[KNN];
        #pragma unroll
        for (int m = 0; m < KNN; ++m) gl[m] = 0xFFFFFFFFu;
        unsigned cnt = cnts[myq];
        bool valid = (cnt >= KNN) && (cnt <= SSTRIDE);
        if (valid) {
            unsigned share = (cnt + 3) >> 2;
            unsigned m0 = h * share;
            unsigned m1 = min(m0 + share, cnt);
            #pragma unroll 1
            for (unsigned m = m0; m < m1; ++m) {
                unsigned k = survl[myq * SSTRIDE + m];
                if (k < gl[KNN - 1]) insert16(k, gl);
            }
        }
        merge4(gl, lane);
        if (valid) {
            // margin check: all filtered-out points provably outside 16th bucket
            float g = g2buf[qg0 + myq];
            float upper = __uint_as_float((gl[KNN - 1] & 0xFFFFE000u) + 0x2000u);
            valid = (upper < g * 0.999f - 1e-5f);
        }
        if (__any((h == 0 && !valid) ? 1 : 0)) {
            if (h == 0 && !valid) {   // exact fallback (P ~ 1e-9/query)
                #pragma unroll
                for (int m = 0; m < KNN; ++m) gl[m] = 0xFFFFFFFFu;
                #pragma unroll 1
                for (int i = 0; i < NPTS; ++i) {
                    float cx = base[i * 3 + 0];
                    float cy = base[i * 3 + 1];
                    float cz = base[i * 3 + 2];
                    float dx = pqx - cx, dy = pqy - cy, dz = pqz - cz;
                    float d2 = dx * dx + dy * dy + dz * dz;
                    unsigned k = mkkey(d2, (unsigned)i);
                    if (k < gl[KNN - 1]) insert16(k, gl);
                }
            }
        }
        if (h == 0) {
            double c00 = 0, c11 = 0, c22 = 0, c01 = 0, c02 = 0, c12 = 0;
            const double qxd = pqx, qyd = pqy, qzd = pqz;
            #pragma unroll
            for (int m = 0; m < KNN; ++m) {
                int idx = (int)(gl[m] & 0x1FFFu);
                double dx = (double)base[idx * 3 + 0] - qxd;
                double dy = (double)base[idx * 3 + 1] - qyd;
                double dz = (double)base[idx * 3 + 2] - qzd;
                c00 += dx * dx; c11 += dy * dy; c22 += dz * dz;
                c01 += dx * dy; c02 += dx * dz; c12 += dy * dz;
            }
            double lmin, lsum;
            eig3(c00, c11, c22, c01, c02, c12, ngx, ngy, ngz, lmin, lsum);
            svg = lmin / lsum;
        }
    } else {
        // Patch kNN: 4 lanes x 64 patch points, gated bubble, butterfly merge.
        unsigned pl[KNN];
        #pragma unroll
        for (int m = 0; m < KNN; ++m) pl[m] = 0xFFFFFFFFu;
        const int j0 = h * 64;
        #pragma unroll 1
        for (int j = j0; j < j0 + 64; ++j) {
            float4 c = pbuf4[j];
            float dx = pqx - c.x, dy = pqy - c.y, dz = pqz - c.z;
            float d2 = dx * dx + dy * dy + dz * dz;
            unsigned k = mkkey(d2, (unsigned)j);
            if (k < pl[KNN - 1]) insert16(k, pl);
        }
        merge4(pl, lane);
        if (h == 0) {
            double c00 = 0, c11 = 0, c22 = 0, c01 = 0, c02 = 0, c12 = 0;
            const double qxd = pqx, qyd = pqy, qzd = pqz;
            #pragma unroll
            for (int m = 0; m < KNN; ++m) {
                int idx = (int)(pl[m] & 0x1FFFu);
                float4 cpt = pbuf4[idx];
                double dx = (double)cpt.x - qxd;
                double dy = (double)cpt.y - qyd;
                double dz = (double)cpt.z - qzd;
                c00 += dx * dx; c11 += dy * dy; c22 += dz * dz;
                c01 += dx * dy; c02 += dx * dz; c12 += dy * dz;
            }
            double nx, ny, nz, lmin, lsum;
            eig3(c00, c11, c22, c01, c02, c12, nx, ny, nz, lmin, lsum);
            xbuf[myq * 4 + 0] = nx;
            xbuf[myq * 4 + 1] = ny;
            xbuf[myq * 4 + 2] = nz;
            xbuf[myq * 4 + 3] = lmin / lsum;
        }
    }
    __syncthreads();   // B2

    double ln = 0.0, lsv = 0.0;
    if (w < 2 && h == 0) {
        double npx = xbuf[myq * 4 + 0];
        double npy = xbuf[myq * 4 + 1];
        double npz = xbuf[myq * 4 + 2];
        double svp = xbuf[myq * 4 + 3];
        double dx = fabs(npx) - fabs(ngx);
        double dy = fabs(npy) - fabs(ngy);
        double dz = fabs(npz) - fabs(ngz);
        ln  = sqrt(dx * dx + dy * dy + dz * dz);
        double ds = svp - svg;
        lsv = ds * ds;
    }
    if (w < 2) {
        #pragma unroll
        for (int o = 32; o > 0; o >>= 1) {
            ln  += __shfl_down(ln, o);
            lsv += __shfl_down(lsv, o);
        }
        if (lane == 0) { rb[w * 2 + 0] = ln; rb[w * 2 + 1] = lsv; }
    }
    __syncthreads();   // B3
    if (t == 0) {
        const double inv = 1.0 / (double)(NBATCH * NPTS);
        atomicAdd(&out[0], (float)((rb[0] + rb[2]) * inv));
        atomicAdd(&out[1], (float)((rb[1] + rb[3]) * inv));
    }
}

// ---------------- legacy monolith (R5) — used only if workspace too small ----
__global__ void __launch_bounds__(256, 4)
spl_main(const float* __restrict__ pts, float* __restrict__ out,
         const unsigned* __restrict__ cellStart, const float4* __restrict__ sortedp)
{
    __shared__ float4 pbuf4[PTCH];
    __shared__ unsigned survk[NQ * SSTRIDE];
    __shared__ unsigned cnts[NQ];
    __shared__ float gbuf[NQ];
    __shared__ double xbuf[NQ * 4];
    __shared__ double rb[4];

    const int t = threadIdx.x;
    const int w = t >> 6;
    const int lane = t & 63;
    const int p = blockIdx.x;
    const int eighth = blockIdx.y;
    const int b = blockIdx.z;

    const float* base = pts + (size_t)b * (NPTS * 3);
    const int qbase = p * PTCH + eighth * NQ;
    const unsigned* cs = cellStart + b * (NCELLS + 1);
    const float4* sp = sortedp + (size_t)b * NPTS;

    {
        const float* src = base + p * (PTCH * 3);
        float* dst = (float*)pbuf4;
        #pragma unroll
        for (int s = 0; s < 3; ++s) {
            int f = t + s * 256;
            int j = f / 3;
            int c = f - 3 * j;
            dst[j * 4 + c] = src[f];
        }
    }
    if (t < NQ) {
        int qi = qbase + t;
        float x = base[qi * 3 + 0], y = base[qi * 3 + 1], z = base[qi * 3 + 2];
        float r = fmaxf(sqrtf(x * x + y * y + z * z), 0.01f);
        float lo = 0.f, hi = 12.f;
        #pragma unroll 1
        for (int it = 0; it < 16; ++it) {
            float mid = 0.5f * (lo + hi);
            if (lam_f(r, mid) < LAMBDA_T) lo = mid; else hi = mid;
        }
        gbuf[t] = hi * hi;
    }
    __syncthreads();

    #pragma unroll 1
    for (int u = 0; u < 8; ++u) {
        const int q = w * 8 + u;
        float4 qv = pbuf4[eighth * NQ + q];
        float qx = rfl(qv.x), qy = rfl(qv.y), qz = rfl(qv.z);
        float g2 = rfl(gbuf[q]);
        float g = sqrtf(g2);
        int ixlo = cidx(qx - g), ixhi = cidx(qx + g);
        int iylo = cidx(qy - g), iyhi = cidx(qy + g);
        int izlo = cidx(qz - g), izhi = cidx(qz + g);
        int nx = ixhi - ixlo + 1;
        int ny = iyhi - iylo + 1;
        int nyz = ny * (izhi - izlo + 1);
        const int lR  = (nyz >= 8) ? 3 : (nyz >= 4) ? 2 : (nyz >= 2) ? 1 : 0;
        const int R   = 1 << lR;
        const int lsl = 6 - lR;
        const unsigned SL = 64u >> lR;
        const unsigned slot = (unsigned)lane & (SL - 1u);
        unsigned cnt = 0;
        unsigned sbase = (unsigned)q * SSTRIDE;
        #pragma unroll 1
        for (int r0 = 0; r0 < nyz; r0 += 64) {
            int r = r0 + lane;
            unsigned pk = 0;
            if (r < nyz) {
                int iz = izlo + r / ny;
                int iy = iylo + (r - (r / ny) * ny);
                int cb = (iz * NC + iy) * NC + ixlo;
                unsigned sB = cs[cb];
                pk = sB | ((cs[cb + nx] - sB) << 14);
            }
            int rmax = min(nyz - r0, 64);
            int gcount = (rmax + R - 1) >> lR;
            #pragma unroll 1
            for (int gg = 0; gg < gcount; ++gg) {
                unsigned pkm = __shfl(pk, (gg << lR) + (lane >> lsl), 64);
                unsigned sBm = pkm & 0x3FFFu;
                unsigned lm  = pkm >> 14;
                #pragma unroll 1
                for (unsigned st = slot; ; st += SL) {
                    bool in = st < lm;
                    if (!__any(in ? 1 : 0)) break;
                    float4 c = sp[min(sBm + st, (unsigned)(NPTS - 1))];
                    float dx = qx - c.x, dy = qy - c.y, dz = qz - c.z;
                    float d2 = dx * dx + dy * dy + dz * dz;
                    bool pass = in && (d2 < g2);
                    unsigned long long m = __ballot(pass);
                    if (pass) {
                        unsigned sw = min(cnt + mbcnt64(m), (unsigned)(SSTRIDE - 1));
                        survk[sbase + sw] = mkkey(d2, __float_as_uint(c.w));
                    }
                    cnt += (unsigned)__popcll(m);
                }
            }
        }
        if (lane == 0) cnts[q] = cnt;
    }
    __syncthreads();

    const int qq = lane >> 2;
    const int h = lane & 3;
    const int myq = (w & 1) * 16 + qq;
    float4 qv = pbuf4[eighth * NQ + myq];
    const float pqx = qv.x, pqy = qv.y, pqz = qv.z;

    double ngx = 0, ngy = 0, ngz = 0, svg = 0;

    if (w < 2) {
        unsigned gl[KNN];
        #pragma unroll
        for (int m = 0; m < KNN; ++m) gl[m] = 0xFFFFFFFFu;
        unsigned cnt = cnts[myq];
        bool valid = (cnt >= KNN) && (cnt <= SSTRIDE);
        if (valid) {
            unsigned share = (cnt + 3) >> 2;
            unsigned m0 = h * share;
            unsigned m1 = min(m0 + share, cnt);
            #pragma unroll 1
            for (unsigned m = m0; m < m1; ++m) {
                unsigned k = survk[myq * SSTRIDE + m];
                if (k < gl[KNN - 1]) insert16(k, gl);
            }
        }
        merge4(gl, lane);
        if (valid) {
            float g = gbuf[myq];
            float upper = __uint_as_float((gl[KNN - 1] & 0xFFFFE000u) + 0x2000u);
            valid = (upper < g * 0.999f - 1e-5f);
        }
        if (__any((h == 0 && !valid) ? 1 : 0)) {
            if (h == 0 && !valid) {
                #pragma unroll
                for (int m = 0; m < KNN; ++m) gl[m] = 0xFFFFFFFFu;
                #pragma unroll 1
                for (int i = 0; i < NPTS; ++i) {
                    float cx = base[i * 3 + 0];
                    float cy = base[i * 3 + 1];
                    float cz = base[i * 3 + 2];
                    float dx = pqx - cx, dy = pqy - cy, dz = pqz - cz;
                    float d2 = dx * dx + dy * dy + dz * dz;
                    unsigned k = mkkey(d2, (unsigned)i);
                    if (k < gl[KNN - 1]) insert16(k, gl);
                }
            }
        }
        if (h == 0) {
            double c00 = 0, c11 = 0, c22 = 0, c01 = 0, c02 = 0, c12 = 0;
            const double qxd = pqx, qyd = pqy, qzd = pqz;
            #pragma unroll
            for (int m = 0; m < KNN; ++m) {
                int idx = (int)(gl[m] & 0x1FFFu);
                double dx = (double)base[idx * 3 + 0] - qxd;
                double dy = (double)base[idx * 3 + 1] - qyd;
                double dz = (double)base[idx * 3 + 2] - qzd;
                c00 += dx * dx; c11 += dy * dy; c22 += dz * dz;
                c01 += dx * dy; c02 += dx * dz; c12 += dy * dz;
            }
            double lmin, lsum;
            eig3(c00, c11, c22, c01, c02, c12, ngx, ngy, ngz, lmin, lsum);
            svg = lmin / lsum;
        }
    } else {
        unsigned pl[KNN];
        #pragma unroll
        for (int m = 0; m < KNN; ++m) pl[m] = 0xFFFFFFFFu;
        const int j0 = h * 64;
        #pragma unroll 1
        for (int j = j0; j < j0 + 64; ++j) {
            float4 c = pbuf4[j];
            float dx = pqx - c.x, dy = pqy - c.y, dz = pqz - c.z;
            float d2 = dx * dx + dy * dy + dz * dz;
            unsigned k = mkkey(d2, (unsigned)j);
            if (k < pl[KNN - 1]) insert16(k, pl);
        }
        merge4(pl, lane);
        if (h == 0) {
            double c00 = 0, c11 = 0, c22 = 0, c01 = 0, c02 = 0, c12 = 0;
            const double qxd = pqx, qyd = pqy, qzd = pqz;
            #pragma unroll
            for (int m = 0; m < KNN; ++m) {
                int idx = (int)(pl[m] & 0x1FFFu);
                float4 cpt = pbuf4[idx];
                double dx = (double)cpt.x - qxd;
                double dy = (double)cpt.y - qyd;
                double dz = (double)cpt.z - qzd;
                c00 += dx * dx; c11 += dy * dy; c22 += dz * dz;
                c01 += dx * dy; c02 += dx * dz; c12 += dy * dz;
            }
            double nx, ny, nz, lmin, lsum;
            eig3(c00, c11, c22, c01, c02, c12, nx, ny, nz, lmin, lsum);
            xbuf[myq * 4 + 0] = nx;
            xbuf[myq * 4 + 1] = ny;
            xbuf[myq * 4 + 2] = nz;
            xbuf[myq * 4 + 3] = lmin / lsum;
        }
    }
    __syncthreads();

    double ln = 0.0, lsv = 0.0;
    if (w < 2 && h == 0) {
        double npx = xbuf[myq * 4 + 0];
        double npy = xbuf[myq * 4 + 1];
        double npz = xbuf[myq * 4 + 2];
        double svp = xbuf[myq * 4 + 3];
        double dx = fabs(npx) - fabs(ngx);
        double dy = fabs(npy) - fabs(ngy);
        double dz = fabs(npz) - fabs(ngz);
        ln  = sqrt(dx * dx + dy * dy + dz * dz);
        double ds = svp - svg;
        lsv = ds * ds;
    }
    if (w < 2) {
        #pragma unroll
        for (int o = 32; o > 0; o >>= 1) {
            ln  += __shfl_down(ln, o);
            lsv += __shfl_down(lsv, o);
        }
        if (lane == 0) { rb[w * 2 + 0] = ln; rb[w * 2 + 1] = lsv; }
    }
    __syncthreads();
    if (t == 0) {
        const double inv = 1.0 / (double)(NBATCH * NPTS);
        atomicAdd(&out[0], (float)((rb[0] + rb[2]) * inv));
        atomicAdd(&out[1], (float)((rb[1] + rb[3]) * inv));
    }
}

extern "C" void kernel_launch(void* const* d_in, const int* in_sizes, int n_in,
                              void* d_out, int out_size, void* d_ws, size_t ws_size,
                              hipStream_t stream)
{
    const float* pts = (const float*)d_in[0];
    float* out = (float*)d_out;

    // workspace carve-up (16B-aligned):
    //   cellStart  @ 0        : 4*4097*4      = 65552
    //   sorted     @ 65552    : 4*8192*16     = 524288   -> 589840
    //   g2buf      @ 589840   : 32768*4       = 131072   -> 720912
    //   cnts       @ 720912   : 32768*4       = 131072   -> 851984
    //   survk      @ 851984   : 32768*130*4   = 17039360 -> 17891344 total
    unsigned char* ws = (unsigned char*)d_ws;
    unsigned* cellStart = (unsigned*)(ws);
    float4*   sorted    = (float4*)  (ws + 65552);
    float*    g2buf     = (float*)   (ws + 589840);
    unsigned* cnts      = (unsigned*)(ws + 720912);
    unsigned* survk     = (unsigned*)(ws + 851984);

    hipLaunchKernelGGL(build_kernel, dim3(NBATCH), dim3(BT), 0, stream,
                       pts, out, cellStart, sorted);
    if (ws_size >= (size_t)17891344) {
        hipLaunchKernelGGL(gate_kernel, dim3(NBATCH * NPTS / 256), dim3(256), 0, stream,
                           pts, g2buf);
        hipLaunchKernelGGL(filter_kernel, dim3(NBATCH * NPTS / 4), dim3(256), 0, stream,
                           pts, g2buf, cellStart, sorted, survk, cnts);
        dim3 grid(NPATCH, 8, NBATCH);
        hipLaunchKernelGGL(select_kernel, grid, dim3(256), 0, stream,
                           pts, out, g2buf, survk, cnts);
    } else {
        dim3 grid(NPATCH, 8, NBATCH);
        hipLaunchKernelGGL(spl_main, grid, dim3(256), 0, stream,
                           pts, out, cellStart, sorted);
    }
}

// Round 7
// 160.915 us; speedup vs baseline: 1.0146x; 1.0072x over previous
//
#include <hip/hip_runtime.h>
#include <math.h>

#define KNN 16
#define NPTS 8192
#define PTCH 256
#define NPATCH 32
#define NBATCH 4
#define NQ 32            // queries per select-block (eighth patch)
#define SSTRIDE 130      // survivor slots/query (mean 64, +8sigma)
#define LAMBDA_T 64.0f   // target E[survivors]/query

// spatial grid
#define NC 16
#define NCELLS (NC * NC * NC)
#define GMIN -4.2f
#define ICS 1.9047619f   // 1 / 0.525 ; NC*0.525 = 8.4 spans [-4.2, 4.2]

// E[#points within distance s of a query at radius r], N iid N(0,I3). fp32.
// Heuristic only: exactness guaranteed by select-phase margin check + fallback.
__device__ __forceinline__ float lam_f(float r, float s)
{
    const float C     = 0.063493636f;    // (2*pi)^{-3/2}
    const float SQ2PI = 2.5066283f;
    const float IS2   = 0.70710678f;
    float a = fabsf(r - s), b = r + s;
    float amr = a - r;
    float coefA = amr * amr + 2.f - s * s;
    float I = 2.f * __expf(-0.5f * b * b) - coefA * __expf(-0.5f * a * a)
            + r * SQ2PI * (erff(b * IS2) - erff(a * IS2));
    float M = C * (3.14159265f / r) * I;
    if (s > r) {
        float u = s - r;
        M += 12.566371f * C * (1.2533141f * erff(u * IS2) - u * __expf(-0.5f * u * u));
    }
    return (float)NPTS * M;
}

// ---------- fp64 cyclic Jacobi 3x3 (verified) ----------
__device__ __forceinline__ void jrot(double& app, double& aqq, double& apq,
                                     double& arp, double& arq,
                                     double& vp0, double& vq0,
                                     double& vp1, double& vq1,
                                     double& vp2, double& vq2)
{
    double g = apq;
    if (g == 0.0) return;
    double theta = (aqq - app) / (2.0 * g);
    double at = fabs(theta);
    double t = (at > 1.0e154) ? (0.5 / theta)
                              : (copysign(1.0, theta) / (at + sqrt(theta * theta + 1.0)));
    double c = 1.0 / sqrt(t * t + 1.0);
    double s = t * c;
    double tau = s / (1.0 + c);
    app -= t * g;
    aqq += t * g;
    apq = 0.0;
    double rp = arp, rq = arq;
    arp = rp - s * (rq + tau * rp);
    arq = rq + s * (rp - tau * rq);
    double p0 = vp0, q0 = vq0;
    vp0 = p0 - s * (q0 + tau * p0); vq0 = q0 + s * (p0 - tau * q0);
    double p1 = vp1, q1 = vq1;
    vp1 = p1 - s * (q1 + tau * p1); vq1 = q1 + s * (p1 - tau * q1);
    double p2 = vp2, q2 = vq2;
    vp2 = p2 - s * (q2 + tau * p2); vq2 = q2 + s * (p2 - tau * q2);
}

__device__ __forceinline__ void eig3(double a00, double a11, double a22,
                                     double a01, double a02, double a12,
                                     double& nx, double& ny, double& nz,
                                     double& lmin, double& lsum)
{
    double v00 = 1, v01 = 0, v02 = 0;
    double v10 = 0, v11 = 1, v12 = 0;
    double v20 = 0, v21 = 0, v22 = 1;
    double scale = fabs(a00) + fabs(a11) + fabs(a22) + fabs(a01) + fabs(a02) + fabs(a12);
    if (scale > 0.0) {
        for (int sweep = 0; sweep < 6; ++sweep) {
            double off = fabs(a01) + fabs(a02) + fabs(a12);
            if (off <= scale * 1e-15) break;
            jrot(a00, a11, a01, a02, a12, v00, v01, v10, v11, v20, v21);
            jrot(a00, a22, a02, a01, a12, v00, v02, v10, v12, v20, v22);
            jrot(a11, a22, a12, a01, a02, v01, v02, v11, v12, v21, v22);
        }
    }
    lsum = a00 + a11 + a22;
    lmin = a00; nx = v00; ny = v10; nz = v20;
    if (a11 < lmin) { lmin = a11; nx = v01; ny = v11; nz = v21; }
    if (a22 < lmin) { lmin = a22; nx = v02; ny = v12; nz = v22; }
}

// u32 key: (d2 float bits, low 13 mantissa bits cleared) | idx(13b). Ties -> lower idx.
__device__ __forceinline__ unsigned mkkey(float d2, unsigned idx) {
    return (__float_as_uint(d2) & 0xFFFFE000u) | idx;
}

// Caller guarantees key < L[15]. Sorted-ascending bubble (v_min/v_max pairs).
__device__ __forceinline__ void insert16(unsigned key, unsigned* L)
{
    L[KNN - 1] = key;
    #pragma unroll
    for (int m = KNN - 1; m >= 1; --m) {
        unsigned a = L[m - 1], b = L[m];
        L[m - 1] = min(a, b);
        L[m]     = max(a, b);
    }
}

// Snapshot-based butterfly merge of sorted 16-lists across lanes h = lane&3.
__device__ __forceinline__ void merge4(unsigned* L, int lane)
{
    #pragma unroll
    for (int step = 1; step <= 2; step <<= 1) {
        unsigned tmp[KNN];
        #pragma unroll
        for (int m = 0; m < KNN; ++m) tmp[m] = __shfl(L[m], lane ^ step, 64);
        for (int m = 0; m < KNN; ++m) {
            if (tmp[m] >= L[KNN - 1]) break;
            insert16(tmp[m], L);
        }
    }
}

__device__ __forceinline__ float rfl(float x) {
    return __int_as_float(__builtin_amdgcn_readfirstlane(__float_as_int(x)));
}
__device__ __forceinline__ unsigned mbcnt64(unsigned long long m) {
    return __builtin_amdgcn_mbcnt_hi((unsigned)(m >> 32),
           __builtin_amdgcn_mbcnt_lo((unsigned)m, 0u));
}

// ---------- grid build ----------
__device__ __forceinline__ int cidx(float v) {
    int i = (int)floorf((v - GMIN) * ICS);
    return min(max(i, 0), NC - 1);
}
__device__ __forceinline__ int cellOf(float x, float y, float z) {
    return (cidx(z) * NC + cidx(y)) * NC + cidx(x);
}

// One block per batch: zero out + histogram + scan + scatter, all in LDS.
#define BT 1024
__global__ void __launch_bounds__(1024)
build_kernel(const float* __restrict__ pts, float* __restrict__ out,
             unsigned* __restrict__ cellStart, float4* __restrict__ sorted)
{
    __shared__ unsigned hist[NCELLS];     // 16 KB; reused as cellPos after scan
    __shared__ unsigned part[BT];         // 4 KB
    const int b = blockIdx.x;
    const int t = threadIdx.x;
    if (b == 0 && t == 0) { out[0] = 0.0f; out[1] = 0.0f; }
    for (int i = t; i < NCELLS; i += BT) hist[i] = 0u;
    __syncthreads();
    const float* base = pts + (size_t)b * (NPTS * 3);
    float px[8], py[8], pz[8];
    int pc[8];
    #pragma unroll
    for (int k = 0; k < 8; ++k) {
        int i = k * BT + t;
        px[k] = base[i * 3 + 0];
        py[k] = base[i * 3 + 1];
        pz[k] = base[i * 3 + 2];
        pc[k] = cellOf(px[k], py[k], pz[k]);
        atomicAdd(&hist[pc[k]], 1u);
    }
    __syncthreads();
    // scan: thread t owns cells t*4 .. t*4+3
    unsigned loc[4], s = 0;
    #pragma unroll
    for (int i = 0; i < 4; ++i) { loc[i] = s; s += hist[t * 4 + i]; }
    part[t] = s;
    __syncthreads();
    for (int o = 1; o < BT; o <<= 1) {
        unsigned u = (t >= o) ? part[t - o] : 0u;
        __syncthreads();
        part[t] += u;
        __syncthreads();
    }
    unsigned basex = part[t] - s;   // exclusive prefix of this thread's 4-cell chunk
    unsigned* csb = cellStart + b * (NCELLS + 1);
    #pragma unroll
    for (int i = 0; i < 4; ++i) {
        unsigned e = basex + loc[i];
        csb[t * 4 + i] = e;
        hist[t * 4 + i] = e;        // becomes running cell position
    }
    if (t == BT - 1) csb[NCELLS] = basex + s;   // == NPTS
    __syncthreads();
    float4* sb = sorted + (size_t)b * NPTS;
    #pragma unroll
    for (int k = 0; k < 8; ++k) {
        int i = k * BT + t;
        unsigned slot = atomicAdd(&hist[pc[k]], 1u);
        float4 v;
        v.x = px[k]; v.y = py[k]; v.z = pz[k]; v.w = __uint_as_float((unsigned)i);
        sb[slot] = v;
    }
}

// One THREAD per query: 32768 gate bisections fully SIMT-parallel.
__global__ void __launch_bounds__(256)
gate_kernel(const float* __restrict__ pts, float* __restrict__ g2buf)
{
    int q = blockIdx.x * 256 + threadIdx.x;     // 0..32767
    int b = q >> 13, i = q & (NPTS - 1);
    const float* pp = pts + (size_t)b * (NPTS * 3) + (size_t)i * 3;
    float x = pp[0], y = pp[1], z = pp[2];
    float r = fmaxf(sqrtf(x * x + y * y + z * z), 0.01f);
    float lo = 0.f, hi = 12.f;
    #pragma unroll 1
    for (int it = 0; it < 16; ++it) {
        float mid = 0.5f * (lo + hi);
        if (lam_f(r, mid) < LAMBDA_T) lo = mid; else hi = mid;
    }
    g2buf[q] = hi * hi;
}

// One WAVE per query (32768 waves): row x slot streaming body, survivors -> global.
__global__ void __launch_bounds__(256)
filter_kernel(const float* __restrict__ pts, const float* __restrict__ g2buf,
              const unsigned* __restrict__ cellStart,
              const float4* __restrict__ sortedp,
              unsigned* __restrict__ survk, unsigned* __restrict__ cnts)
{
    const int lane = threadIdx.x & 63;
    const int wq = __builtin_amdgcn_readfirstlane(
        (int)((blockIdx.x * 256u + (unsigned)threadIdx.x) >> 6));  // query id
    const int b  = wq >> 13;
    const int qi = wq & (NPTS - 1);
    const float* base = pts + (size_t)b * (NPTS * 3);
    const unsigned* cs = cellStart + b * (NCELLS + 1);
    const float4* sp = sortedp + (size_t)b * NPTS;

    const float qx = base[qi * 3 + 0];   // wave-uniform scalar loads
    const float qy = base[qi * 3 + 1];
    const float qz = base[qi * 3 + 2];
    const float g2 = g2buf[wq];
    const float g  = sqrtf(g2);

    int ixlo = cidx(qx - g), ixhi = cidx(qx + g);
    int iylo = cidx(qy - g), iyhi = cidx(qy + g);
    int izlo = cidx(qz - g), izhi = cidx(qz + g);
    int nx = ixhi - ixlo + 1;
    int ny = iyhi - iylo + 1;
    int nyz = ny * (izhi - izlo + 1);
    const int lR  = (nyz >= 8) ? 3 : (nyz >= 4) ? 2 : (nyz >= 2) ? 1 : 0;
    const int R   = 1 << lR;
    const int lsl = 6 - lR;
    const unsigned SL = 64u >> lR;
    const unsigned slot = (unsigned)lane & (SL - 1u);
    unsigned cnt = 0;                          // wave-uniform by construction
    unsigned sbase = (unsigned)wq * SSTRIDE;
    #pragma unroll 1
    for (int r0 = 0; r0 < nyz; r0 += 64) {
        int r = r0 + lane;
        unsigned pk = 0;
        if (r < nyz) {
            int iz = izlo + r / ny;
            int iy = iylo + (r - (r / ny) * ny);
            int cb = (iz * NC + iy) * NC + ixlo;
            unsigned sB = cs[cb];
            pk = sB | ((cs[cb + nx] - sB) << 14);
        }
        int rmax = min(nyz - r0, 64);
        int gcount = (rmax + R - 1) >> lR;
        #pragma unroll 1
        for (int gg = 0; gg < gcount; ++gg) {
            unsigned pkm = __shfl(pk, (gg << lR) + (lane >> lsl), 64);
            unsigned sBm = pkm & 0x3FFFu;
            unsigned lm  = pkm >> 14;
            #pragma unroll 1
            for (unsigned st = slot; ; st += SL) {
                bool in = st < lm;
                if (!__any(in ? 1 : 0)) break;
                float4 c = sp[min(sBm + st, (unsigned)(NPTS - 1))];
                float dx = qx - c.x, dy = qy - c.y, dz = qz - c.z;
                float d2 = dx * dx + dy * dy + dz * dz;   // reference-form d2
                bool pass = in && (d2 < g2);
                unsigned long long m = __ballot(pass);
                if (pass) {
                    unsigned sw = min(cnt + mbcnt64(m), (unsigned)(SSTRIDE - 1));
                    survk[sbase + sw] = mkkey(d2, __float_as_uint(c.w));
                }
                cnt += (unsigned)__popcll(m);
            }
        }
    }
    if (lane == 0) cnts[wq] = cnt;
}

// Block = 256 threads, 32 queries; grid 1024. Select + eig + per-block partial.
// R7: NO output atomics (partials -> ws; was 2048 same-address device atomics
// from simultaneously-finishing blocks = suspected serialization tail), and
// unroll-4 on the LDS scan loops to pipeline the ~120cy LDS latency.
__global__ void __launch_bounds__(256, 4)
select_kernel(const float* __restrict__ pts,
              const float* __restrict__ g2buf,
              const unsigned* __restrict__ survk_g,
              const unsigned* __restrict__ cnts_g,
              double* __restrict__ partials)
{
    __shared__ float4 pbuf4[PTCH];                 // 4 KB own patch
    __shared__ unsigned survl[NQ * SSTRIDE];       // 16.6 KB survivor keys
    __shared__ unsigned cnts[NQ];
    __shared__ double xbuf[NQ * 4];                // patch normal+sv
    __shared__ double rb[4];                       // partials

    const int t = threadIdx.x;
    const int w = t >> 6;
    const int lane = t & 63;
    const int p = blockIdx.x;
    const int eighth = blockIdx.y;
    const int b = blockIdx.z;

    const float* base = pts + (size_t)b * (NPTS * 3);
    const int qbase = p * PTCH + eighth * NQ;
    const int qg0 = b * NPTS + qbase;              // block's first global query id

    // Stage own patch into padded LDS.
    {
        const float* src = base + p * (PTCH * 3);
        float* dst = (float*)pbuf4;
        #pragma unroll
        for (int s = 0; s < 3; ++s) {
            int f = t + s * 256;
            int j = f / 3;
            int c = f - 3 * j;
            dst[j * 4 + c] = src[f];
        }
    }
    // Stage survivors (fully coalesced rows) + counts.
    {
        const unsigned* src = survk_g + (size_t)qg0 * SSTRIDE;
        #pragma unroll 1
        for (int i = t; i < NQ * SSTRIDE; i += 256) survl[i] = src[i];
        if (t < NQ) cnts[t] = cnts_g[qg0 + t];
    }
    __syncthreads();

    // ---- 4 lanes per query ----
    const int qq = lane >> 2;            // query within half 0..15
    const int h = lane & 3;              // sub-lane
    const int myq = (w & 1) * 16 + qq;   // query 0..31
    float4 qv = pbuf4[eighth * NQ + myq];
    const float pqx = qv.x, pqy = qv.y, pqz = qv.z;

    double ngx = 0, ngy = 0, ngz = 0, svg = 0;

    if (w < 2) {
        // Global top-16: split survivor keys 4 ways, gated bubble, butterfly merge.
        unsigned gl[KNN];
        #pragma unroll
        for (int m = 0; m < KNN; ++m) gl[m] = 0xFFFFFFFFu;
        unsigned cnt = cnts[myq];
        bool valid = (cnt >= KNN) && (cnt <= SSTRIDE);
        if (valid) {
            unsigned share = (cnt + 3) >> 2;
            unsigned m0 = h * share;
            unsigned m1 = min(m0 + share, cnt);
            #pragma unroll 4
            for (unsigned m = m0; m < m1; ++m) {
                unsigned k = survl[myq * SSTRIDE + m];
                if (k < gl[KNN - 1]) insert16(k, gl);
            }
        }
        merge4(gl, lane);
        if (valid) {
            // margin check: all filtered-out points provably outside 16th bucket
            float g = g2buf[qg0 + myq];
            float upper = __uint_as_float((gl[KNN - 1] & 0xFFFFE000u) + 0x2000u);
            valid = (upper < g * 0.999f - 1e-5f);
        }
        if (__any((h == 0 && !valid) ? 1 : 0)) {
            if (h == 0 && !valid) {   // exact fallback (P ~ 1e-9/query)
                #pragma unroll
                for (int m = 0; m < KNN; ++m) gl[m] = 0xFFFFFFFFu;
                #pragma unroll 1
                for (int i = 0; i < NPTS; ++i) {
                    float cx = base[i * 3 + 0];
                    float cy = base[i * 3 + 1];
                    float cz = base[i * 3 + 2];
                    float dx = pqx - cx, dy = pqy - cy, dz = pqz - cz;
                    float d2 = dx * dx + dy * dy + dz * dz;
                    unsigned k = mkkey(d2, (unsigned)i);
                    if (k < gl[KNN - 1]) insert16(k, gl);
                }
            }
        }
        if (h == 0) {
            double c00 = 0, c11 = 0, c22 = 0, c01 = 0, c02 = 0, c12 = 0;
            const double qxd = pqx, qyd = pqy, qzd = pqz;
            #pragma unroll
            for (int m = 0; m < KNN; ++m) {
                int idx = (int)(gl[m] & 0x1FFFu);
                double dx = (double)base[idx * 3 + 0] - qxd;
                double dy = (double)base[idx * 3 + 1] - qyd;
                double dz = (double)base[idx * 3 + 2] - qzd;
                c00 += dx * dx; c11 += dy * dy; c22 += dz * dz;
                c01 += dx * dy; c02 += dx * dz; c12 += dy * dz;
            }
            double lmin, lsum;
            eig3(c00, c11, c22, c01, c02, c12, ngx, ngy, ngz, lmin, lsum);
            svg = lmin / lsum;
        }
    } else {
        // Patch kNN: 4 lanes x 64 patch points, gated bubble, butterfly merge.
        unsigned pl[KNN];
        #pragma unroll
        for (int m = 0; m < KNN; ++m) pl[m] = 0xFFFFFFFFu;
        const int j0 = h * 64;
        #pragma unroll 4
        for (int j = j0; j < j0 + 64; ++j) {
            float4 c = pbuf4[j];
            float dx = pqx - c.x, dy = pqy - c.y, dz = pqz - c.z;
            float d2 = dx * dx + dy * dy + dz * dz;
            unsigned k = mkkey(d2, (unsigned)j);
            if (k < pl[KNN - 1]) insert16(k, pl);
        }
        merge4(pl, lane);
        if (h == 0) {
            double c00 = 0, c11 = 0, c22 = 0, c01 = 0, c02 = 0, c12 = 0;
            const double qxd = pqx, qyd = pqy, qzd = pqz;
            #pragma unroll
            for (int m = 0; m < KNN; ++m) {
                int idx = (int)(pl[m] & 0x1FFFu);
                float4 cpt = pbuf4[idx];
                double dx = (double)cpt.x - qxd;
                double dy = (double)cpt.y - qyd;
                double dz = (double)cpt.z - qzd;
                c00 += dx * dx; c11 += dy * dy; c22 += dz * dz;
                c01 += dx * dy; c02 += dx * dz; c12 += dy * dz;
            }
            double nx, ny, nz, lmin, lsum;
            eig3(c00, c11, c22, c01, c02, c12, nx, ny, nz, lmin, lsum);
            xbuf[myq * 4 + 0] = nx;
            xbuf[myq * 4 + 1] = ny;
            xbuf[myq * 4 + 2] = nz;
            xbuf[myq * 4 + 3] = lmin / lsum;
        }
    }
    __syncthreads();   // B2

    double ln = 0.0, lsv = 0.0;
    if (w < 2 && h == 0) {
        double npx = xbuf[myq * 4 + 0];
        double npy = xbuf[myq * 4 + 1];
        double npz = xbuf[myq * 4 + 2];
        double svp = xbuf[myq * 4 + 3];
        double dx = fabs(npx) - fabs(ngx);
        double dy = fabs(npy) - fabs(ngy);
        double dz = fabs(npz) - fabs(ngz);
        ln  = sqrt(dx * dx + dy * dy + dz * dz);
        double ds = svp - svg;
        lsv = ds * ds;
    }
    if (w < 2) {
        #pragma unroll
        for (int o = 32; o > 0; o >>= 1) {
            ln  += __shfl_down(ln, o);
            lsv += __shfl_down(lsv, o);
        }
        if (lane == 0) { rb[w * 2 + 0] = ln; rb[w * 2 + 1] = lsv; }
    }
    __syncthreads();   // B3
    if (t == 0) {
        const int bf = (b * 8 + eighth) * NPATCH + p;   // 0..1023
        partials[bf * 2 + 0] = rb[0] + rb[2];
        partials[bf * 2 + 1] = rb[1] + rb[3];
    }
}

// 1 block: deterministic fixed-order double sum of 1024 partial pairs.
__global__ void __launch_bounds__(256)
reduce_kernel(const double* __restrict__ partials, float* __restrict__ out)
{
    __shared__ double sln[4], slv[4];
    const int t = threadIdx.x;
    double a = 0.0, c = 0.0;
    #pragma unroll
    for (int k = 0; k < 4; ++k) {
        int i = t + k * 256;           // 0..1023
        a += partials[i * 2 + 0];
        c += partials[i * 2 + 1];
    }
    #pragma unroll
    for (int o = 32; o > 0; o >>= 1) {
        a += __shfl_down(a, o);
        c += __shfl_down(c, o);
    }
    if ((t & 63) == 0) { sln[t >> 6] = a; slv[t >> 6] = c; }
    __syncthreads();
    if (t == 0) {
        const double inv = 1.0 / (double)(NBATCH * NPTS);
        out[0] = (float)((sln[0] + sln[1] + sln[2] + sln[3]) * inv);
        out[1] = (float)((slv[0] + slv[1] + slv[2] + slv[3]) * inv);
    }
}

// ---------------- legacy monolith (R5) — used only if workspace too small ----
__global__ void __launch_bounds__(256, 4)
spl_main(const float* __restrict__ pts, float* __restrict__ out,
         const unsigned* __restrict__ cellStart, const float4* __restrict__ sortedp)
{
    __shared__ float4 pbuf4[PTCH];
    __shared__ unsigned survk[NQ * SSTRIDE];
    __shared__ unsigned cnts[NQ];
    __shared__ float gbuf[NQ];
    __shared__ double xbuf[NQ * 4];
    __shared__ double rb[4];

    const int t = threadIdx.x;
    const int w = t >> 6;
    const int lane = t & 63;
    const int p = blockIdx.x;
    const int eighth = blockIdx.y;
    const int b = blockIdx.z;

    const float* base = pts + (size_t)b * (NPTS * 3);
    const int qbase = p * PTCH + eighth * NQ;
    const unsigned* cs = cellStart + b * (NCELLS + 1);
    const float4* sp = sortedp + (size_t)b * NPTS;

    {
        const float* src = base + p * (PTCH * 3);
        float* dst = (float*)pbuf4;
        #pragma unroll
        for (int s = 0; s < 3; ++s) {
            int f = t + s * 256;
            int j = f / 3;
            int c = f - 3 * j;
            dst[j * 4 + c] = src[f];
        }
    }
    if (t < NQ) {
        int qi = qbase + t;
        float x = base[qi * 3 + 0], y = base[qi * 3 + 1], z = base[qi * 3 + 2];
        float r = fmaxf(sqrtf(x * x + y * y + z * z), 0.01f);
        float lo = 0.f, hi = 12.f;
        #pragma unroll 1
        for (int it = 0; it < 16; ++it) {
            float mid = 0.5f * (lo + hi);
            if (lam_f(r, mid) < LAMBDA_T) lo = mid; else hi = mid;
        }
        gbuf[t] = hi * hi;
    }
    __syncthreads();

    #pragma unroll 1
    for (int u = 0; u < 8; ++u) {
        const int q = w * 8 + u;
        float4 qv = pbuf4[eighth * NQ + q];
        float qx = rfl(qv.x), qy = rfl(qv.y), qz = rfl(qv.z);
        float g2 = rfl(gbuf[q]);
        float g = sqrtf(g2);
        int ixlo = cidx(qx - g), ixhi = cidx(qx + g);
        int iylo = cidx(qy - g), iyhi = cidx(qy + g);
        int izlo = cidx(qz - g), izhi = cidx(qz + g);
        int nx = ixhi - ixlo + 1;
        int ny = iyhi - iylo + 1;
        int nyz = ny * (izhi - izlo + 1);
        const int lR  = (nyz >= 8) ? 3 : (nyz >= 4) ? 2 : (nyz >= 2) ? 1 : 0;
        const int R   = 1 << lR;
        const int lsl = 6 - lR;
        const unsigned SL = 64u >> lR;
        const unsigned slot = (unsigned)lane & (SL - 1u);
        unsigned cnt = 0;
        unsigned sbase = (unsigned)q * SSTRIDE;
        #pragma unroll 1
        for (int r0 = 0; r0 < nyz; r0 += 64) {
            int r = r0 + lane;
            unsigned pk = 0;
            if (r < nyz) {
                int iz = izlo + r / ny;
                int iy = iylo + (r - (r / ny) * ny);
                int cb = (iz * NC + iy) * NC + ixlo;
                unsigned sB = cs[cb];
                pk = sB | ((cs[cb + nx] - sB) << 14);
            }
            int rmax = min(nyz - r0, 64);
            int gcount = (rmax + R - 1) >> lR;
            #pragma unroll 1
            for (int gg = 0; gg < gcount; ++gg) {
                unsigned pkm = __shfl(pk, (gg << lR) + (lane >> lsl), 64);
                unsigned sBm = pkm & 0x3FFFu;
                unsigned lm  = pkm >> 14;
                #pragma unroll 1
                for (unsigned st = slot; ; st += SL) {
                    bool in = st < lm;
                    if (!__any(in ? 1 : 0)) break;
                    float4 c = sp[min(sBm + st, (unsigned)(NPTS - 1))];
                    float dx = qx - c.x, dy = qy - c.y, dz = qz - c.z;
                    float d2 = dx * dx + dy * dy + dz * dz;
                    bool pass = in && (d2 < g2);
                    unsigned long long m = __ballot(pass);
                    if (pass) {
                        unsigned sw = min(cnt + mbcnt64(m), (unsigned)(SSTRIDE - 1));
                        survk[sbase + sw] = mkkey(d2, __float_as_uint(c.w));
                    }
                    cnt += (unsigned)__popcll(m);
                }
            }
        }
        if (lane == 0) cnts[q] = cnt;
    }
    __syncthreads();

    const int qq = lane >> 2;
    const int h = lane & 3;
    const int myq = (w & 1) * 16 + qq;
    float4 qv = pbuf4[eighth * NQ + myq];
    const float pqx = qv.x, pqy = qv.y, pqz = qv.z;

    double ngx = 0, ngy = 0, ngz = 0, svg = 0;

    if (w < 2) {
        unsigned gl[KNN];
        #pragma unroll
        for (int m = 0; m < KNN; ++m) gl[m] = 0xFFFFFFFFu;
        unsigned cnt = cnts[myq];
        bool valid = (cnt >= KNN) && (cnt <= SSTRIDE);
        if (valid) {
            unsigned share = (cnt + 3) >> 2;
            unsigned m0 = h * share;
            unsigned m1 = min(m0 + share, cnt);
            #pragma unroll 1
            for (unsigned m = m0; m < m1; ++m) {
                unsigned k = survk[myq * SSTRIDE + m];
                if (k < gl[KNN - 1]) insert16(k, gl);
            }
        }
        merge4(gl, lane);
        if (valid) {
            float g = gbuf[myq];
            float upper = __uint_as_float((gl[KNN - 1] & 0xFFFFE000u) + 0x2000u);
            valid = (upper < g * 0.999f - 1e-5f);
        }
        if (__any((h == 0 && !valid) ? 1 : 0)) {
            if (h == 0 && !valid) {
                #pragma unroll
                for (int m = 0; m < KNN; ++m) gl[m] = 0xFFFFFFFFu;
                #pragma unroll 1
                for (int i = 0; i < NPTS; ++i) {
                    float cx = base[i * 3 + 0];
                    float cy = base[i * 3 + 1];
                    float cz = base[i * 3 + 2];
                    float dx = pqx - cx, dy = pqy - cy, dz = pqz - cz;
                    float d2 = dx * dx + dy * dy + dz * dz;
                    unsigned k = mkkey(d2, (unsigned)i);
                    if (k < gl[KNN - 1]) insert16(k, gl);
                }
            }
        }
        if (h == 0) {
            double c00 = 0, c11 = 0, c22 = 0, c01 = 0, c02 = 0, c12 = 0;
            const double qxd = pqx, qyd = pqy, qzd = pqz;
            #pragma unroll
            for (int m = 0; m < KNN; ++m) {
                int idx = (int)(gl[m] & 0x1FFFu);
                double dx = (double)base[idx * 3 + 0] - qxd;
                double dy = (double)base[idx * 3 + 1] - qyd;
                double dz = (double)base[idx * 3 + 2] - qzd;
                c00 += dx * dx; c11 += dy * dy; c22 += dz * dz;
                c01 += dx * dy; c02 += dx * dz; c12 += dy * dz;
            }
            double lmin, lsum;
            eig3(c00, c11, c22, c01, c02, c12, ngx, ngy, ngz, lmin, lsum);
            svg = lmin / lsum;
        }
    } else {
        unsigned pl[KNN];
        #pragma unroll
        for (int m = 0; m < KNN; ++m) pl[m] = 0xFFFFFFFFu;
        const int j0 = h * 64;
        #pragma unroll 1
        for (int j = j0; j < j0 + 64; ++j) {
            float4 c = pbuf4[j];
            float dx = pqx - c.x, dy = pqy - c.y, dz = pqz - c.z;
            float d2 = dx * dx + dy * dy + dz * dz;
            unsigned k = mkkey(d2, (unsigned)j);
            if (k < pl[KNN - 1]) insert16(k, pl);
        }
        merge4(pl, lane);
        if (h == 0) {
            double c00 = 0, c11 = 0, c22 = 0, c01 = 0, c02 = 0, c12 = 0;
            const double qxd = pqx, qyd = pqy, qzd = pqz;
            #pragma unroll
            for (int m = 0; m < KNN; ++m) {
                int idx = (int)(pl[m] & 0x1FFFu);
                float4 cpt = pbuf4[idx];
                double dx = (double)cpt.x - qxd;
                double dy = (double)cpt.y - qyd;
                double dz = (double)cpt.z - qzd;
                c00 += dx * dx; c11 += dy * dy; c22 += dz * dz;
                c01 += dx * dy; c02 += dx * dz; c12 += dy * dz;
            }
            double nx, ny, nz, lmin, lsum;
            eig3(c00, c11, c22, c01, c02, c12, nx, ny, nz, lmin, lsum);
            xbuf[myq * 4 + 0] = nx;
            xbuf[myq * 4 + 1] = ny;
            xbuf[myq * 4 + 2] = nz;
            xbuf[myq * 4 + 3] = lmin / lsum;
        }
    }
    __syncthreads();

    double ln = 0.0, lsv = 0.0;
    if (w < 2 && h == 0) {
        double npx = xbuf[myq * 4 + 0];
        double npy = xbuf[myq * 4 + 1];
        double npz = xbuf[myq * 4 + 2];
        double svp = xbuf[myq * 4 + 3];
        double dx = fabs(npx) - fabs(ngx);
        double dy = fabs(npy) - fabs(ngy);
        double dz = fabs(npz) - fabs(ngz);
        ln  = sqrt(dx * dx + dy * dy + dz * dz);
        double ds = svp - svg;
        lsv = ds * ds;
    }
    if (w < 2) {
        #pragma unroll
        for (int o = 32; o > 0; o >>= 1) {
            ln  += __shfl_down(ln, o);
            lsv += __shfl_down(lsv, o);
        }
        if (lane == 0) { rb[w * 2 + 0] = ln; rb[w * 2 + 1] = lsv; }
    }
    __syncthreads();
    if (t == 0) {
        const double inv = 1.0 / (double)(NBATCH * NPTS);
        atomicAdd(&out[0], (float)((rb[0] + rb[2]) * inv));
        atomicAdd(&out[1], (float)((rb[1] + rb[3]) * inv));
    }
}

extern "C" void kernel_launch(void* const* d_in, const int* in_sizes, int n_in,
                              void* d_out, int out_size, void* d_ws, size_t ws_size,
                              hipStream_t stream)
{
    const float* pts = (const float*)d_in[0];
    float* out = (float*)d_out;

    // workspace carve-up (16B-aligned):
    //   cellStart  @ 0        : 4*4097*4      = 65552
    //   sorted     @ 65552    : 4*8192*16     = 524288   -> 589840
    //   g2buf      @ 589840   : 32768*4       = 131072   -> 720912
    //   cnts       @ 720912   : 32768*4       = 131072   -> 851984
    //   survk      @ 851984   : 32768*130*4   = 17039360 -> 17891344
    //   partials   @ 17891344 : 1024*2*8      = 16384    -> 17907728 total
    unsigned char* ws = (unsigned char*)d_ws;
    unsigned* cellStart = (unsigned*)(ws);
    float4*   sorted    = (float4*)  (ws + 65552);
    float*    g2buf     = (float*)   (ws + 589840);
    unsigned* cnts      = (unsigned*)(ws + 720912);
    unsigned* survk     = (unsigned*)(ws + 851984);
    double*   partials  = (double*)  (ws + 17891344);

    hipLaunchKernelGGL(build_kernel, dim3(NBATCH), dim3(BT), 0, stream,
                       pts, out, cellStart, sorted);
    if (ws_size >= (size_t)17907728) {
        hipLaunchKernelGGL(gate_kernel, dim3(NBATCH * NPTS / 256), dim3(256), 0, stream,
                           pts, g2buf);
        hipLaunchKernelGGL(filter_kernel, dim3(NBATCH * NPTS / 4), dim3(256), 0, stream,
                           pts, g2buf, cellStart, sorted, survk, cnts);
        dim3 grid(NPATCH, 8, NBATCH);
        hipLaunchKernelGGL(select_kernel, grid, dim3(256), 0, stream,
                           pts, g2buf, survk, cnts, partials);
        hipLaunchKernelGGL(reduce_kernel, dim3(1), dim3(256), 0, stream,
                           partials, out);
    } else {
        dim3 grid(NPATCH, 8, NBATCH);
        hipLaunchKernelGGL(spl_main, grid, dim3(256), 0, stream,
                           pts, out, cellStart, sorted);
    }
}

// Round 8
// 157.024 us; speedup vs baseline: 1.0397x; 1.0248x over previous
//
#include <hip/hip_runtime.h>
#include <math.h>

#define KNN 16
#define NPTS 8192
#define PTCH 256
#define NPATCH 32
#define NBATCH 4
#define NQ 32            // queries per select-block (eighth patch)
#define SSTRIDE 130      // survivor slots/query (mean 64, +8sigma)
#define LAMBDA_T 64.0f   // target E[survivors]/query

// spatial grid
#define NC 16
#define NCELLS (NC * NC * NC)
#define GMIN -4.2f
#define ICS 1.9047619f   // 1 / 0.525 ; NC*0.525 = 8.4 spans [-4.2, 4.2]

// E[#points within distance s of a query at radius r], N iid N(0,I3). fp32.
// Heuristic only: exactness guaranteed by select-phase margin check + fallback.
__device__ __forceinline__ float lam_f(float r, float s)
{
    const float C     = 0.063493636f;    // (2*pi)^{-3/2}
    const float SQ2PI = 2.5066283f;
    const float IS2   = 0.70710678f;
    float a = fabsf(r - s), b = r + s;
    float amr = a - r;
    float coefA = amr * amr + 2.f - s * s;
    float I = 2.f * __expf(-0.5f * b * b) - coefA * __expf(-0.5f * a * a)
            + r * SQ2PI * (erff(b * IS2) - erff(a * IS2));
    float M = C * (3.14159265f / r) * I;
    if (s > r) {
        float u = s - r;
        M += 12.566371f * C * (1.2533141f * erff(u * IS2) - u * __expf(-0.5f * u * u));
    }
    return (float)NPTS * M;
}

// ---------- fp64 cyclic Jacobi 3x3 (verified) ----------
__device__ __forceinline__ void jrot(double& app, double& aqq, double& apq,
                                     double& arp, double& arq,
                                     double& vp0, double& vq0,
                                     double& vp1, double& vq1,
                                     double& vp2, double& vq2)
{
    double g = apq;
    if (g == 0.0) return;
    double theta = (aqq - app) / (2.0 * g);
    double at = fabs(theta);
    double t = (at > 1.0e154) ? (0.5 / theta)
                              : (copysign(1.0, theta) / (at + sqrt(theta * theta + 1.0)));
    double c = 1.0 / sqrt(t * t + 1.0);
    double s = t * c;
    double tau = s / (1.0 + c);
    app -= t * g;
    aqq += t * g;
    apq = 0.0;
    double rp = arp, rq = arq;
    arp = rp - s * (rq + tau * rp);
    arq = rq + s * (rp - tau * rq);
    double p0 = vp0, q0 = vq0;
    vp0 = p0 - s * (q0 + tau * p0); vq0 = q0 + s * (p0 - tau * q0);
    double p1 = vp1, q1 = vq1;
    vp1 = p1 - s * (q1 + tau * p1); vq1 = q1 + s * (p1 - tau * q1);
    double p2 = vp2, q2 = vq2;
    vp2 = p2 - s * (q2 + tau * p2); vq2 = q2 + s * (p2 - tau * q2);
}

__device__ __forceinline__ void eig3(double a00, double a11, double a22,
                                     double a01, double a02, double a12,
                                     double& nx, double& ny, double& nz,
                                     double& lmin, double& lsum)
{
    double v00 = 1, v01 = 0, v02 = 0;
    double v10 = 0, v11 = 1, v12 = 0;
    double v20 = 0, v21 = 0, v22 = 1;
    double scale = fabs(a00) + fabs(a11) + fabs(a22) + fabs(a01) + fabs(a02) + fabs(a12);
    if (scale > 0.0) {
        for (int sweep = 0; sweep < 6; ++sweep) {
            double off = fabs(a01) + fabs(a02) + fabs(a12);
            if (off <= scale * 1e-15) break;
            jrot(a00, a11, a01, a02, a12, v00, v01, v10, v11, v20, v21);
            jrot(a00, a22, a02, a01, a12, v00, v02, v10, v12, v20, v22);
            jrot(a11, a22, a12, a01, a02, v01, v02, v11, v12, v21, v22);
        }
    }
    lsum = a00 + a11 + a22;
    lmin = a00; nx = v00; ny = v10; nz = v20;
    if (a11 < lmin) { lmin = a11; nx = v01; ny = v11; nz = v21; }
    if (a22 < lmin) { lmin = a22; nx = v02; ny = v12; nz = v22; }
}

// u32 key: (d2 float bits, low 13 mantissa bits cleared) | idx(13b). Ties -> lower idx.
__device__ __forceinline__ unsigned mkkey(float d2, unsigned idx) {
    return (__float_as_uint(d2) & 0xFFFFE000u) | idx;
}

// Caller guarantees key < L[15]. Sorted-ascending bubble (v_min/v_max pairs).
__device__ __forceinline__ void insert16(unsigned key, unsigned* L)
{
    L[KNN - 1] = key;
    #pragma unroll
    for (int m = KNN - 1; m >= 1; --m) {
        unsigned a = L[m - 1], b = L[m];
        L[m - 1] = min(a, b);
        L[m]     = max(a, b);
    }
}

// Snapshot-based butterfly merge of sorted 16-lists across lanes h = lane&3.
__device__ __forceinline__ void merge4(unsigned* L, int lane)
{
    #pragma unroll
    for (int step = 1; step <= 2; step <<= 1) {
        unsigned tmp[KNN];
        #pragma unroll
        for (int m = 0; m < KNN; ++m) tmp[m] = __shfl(L[m], lane ^ step, 64);
        for (int m = 0; m < KNN; ++m) {
            if (tmp[m] >= L[KNN - 1]) break;
            insert16(tmp[m], L);
        }
    }
}

__device__ __forceinline__ float rfl(float x) {
    return __int_as_float(__builtin_amdgcn_readfirstlane(__float_as_int(x)));
}
__device__ __forceinline__ unsigned mbcnt64(unsigned long long m) {
    return __builtin_amdgcn_mbcnt_hi((unsigned)(m >> 32),
           __builtin_amdgcn_mbcnt_lo((unsigned)m, 0u));
}

// ---------- grid build ----------
__device__ __forceinline__ int cidx(float v) {
    int i = (int)floorf((v - GMIN) * ICS);
    return min(max(i, 0), NC - 1);
}
__device__ __forceinline__ int cellOf(float x, float y, float z) {
    return (cidx(z) * NC + cidx(y)) * NC + cidx(x);
}

// One block per batch: zero out + histogram + scan + scatter, all in LDS.
#define BT 1024
__global__ void __launch_bounds__(1024)
build_kernel(const float* __restrict__ pts, float* __restrict__ out,
             unsigned* __restrict__ cellStart, float4* __restrict__ sorted)
{
    __shared__ unsigned hist[NCELLS];     // 16 KB; reused as cellPos after scan
    __shared__ unsigned part[BT];         // 4 KB
    const int b = blockIdx.x;
    const int t = threadIdx.x;
    if (b == 0 && t == 0) { out[0] = 0.0f; out[1] = 0.0f; }
    for (int i = t; i < NCELLS; i += BT) hist[i] = 0u;
    __syncthreads();
    const float* base = pts + (size_t)b * (NPTS * 3);
    float px[8], py[8], pz[8];
    int pc[8];
    #pragma unroll
    for (int k = 0; k < 8; ++k) {
        int i = k * BT + t;
        px[k] = base[i * 3 + 0];
        py[k] = base[i * 3 + 1];
        pz[k] = base[i * 3 + 2];
        pc[k] = cellOf(px[k], py[k], pz[k]);
        atomicAdd(&hist[pc[k]], 1u);
    }
    __syncthreads();
    // scan: thread t owns cells t*4 .. t*4+3
    unsigned loc[4], s = 0;
    #pragma unroll
    for (int i = 0; i < 4; ++i) { loc[i] = s; s += hist[t * 4 + i]; }
    part[t] = s;
    __syncthreads();
    for (int o = 1; o < BT; o <<= 1) {
        unsigned u = (t >= o) ? part[t - o] : 0u;
        __syncthreads();
        part[t] += u;
        __syncthreads();
    }
    unsigned basex = part[t] - s;   // exclusive prefix of this thread's 4-cell chunk
    unsigned* csb = cellStart + b * (NCELLS + 1);
    #pragma unroll
    for (int i = 0; i < 4; ++i) {
        unsigned e = basex + loc[i];
        csb[t * 4 + i] = e;
        hist[t * 4 + i] = e;        // becomes running cell position
    }
    if (t == BT - 1) csb[NCELLS] = basex + s;   // == NPTS
    __syncthreads();
    float4* sb = sorted + (size_t)b * NPTS;
    #pragma unroll
    for (int k = 0; k < 8; ++k) {
        int i = k * BT + t;
        unsigned slot = atomicAdd(&hist[pc[k]], 1u);
        float4 v;
        v.x = px[k]; v.y = py[k]; v.z = pz[k]; v.w = __uint_as_float((unsigned)i);
        sb[slot] = v;
    }
}

// One THREAD per query: 32768 gate bisections fully SIMT-parallel.
__global__ void __launch_bounds__(256)
gate_kernel(const float* __restrict__ pts, float* __restrict__ g2buf)
{
    int q = blockIdx.x * 256 + threadIdx.x;     // 0..32767
    int b = q >> 13, i = q & (NPTS - 1);
    const float* pp = pts + (size_t)b * (NPTS * 3) + (size_t)i * 3;
    float x = pp[0], y = pp[1], z = pp[2];
    float r = fmaxf(sqrtf(x * x + y * y + z * z), 0.01f);
    float lo = 0.f, hi = 12.f;
    #pragma unroll 1
    for (int it = 0; it < 16; ++it) {
        float mid = 0.5f * (lo + hi);
        if (lam_f(r, mid) < LAMBDA_T) lo = mid; else hi = mid;
    }
    g2buf[q] = hi * hi;
}

// One WAVE per query (32768 waves): row x slot streaming body, survivors -> global.
__global__ void __launch_bounds__(256)
filter_kernel(const float* __restrict__ pts, const float* __restrict__ g2buf,
              const unsigned* __restrict__ cellStart,
              const float4* __restrict__ sortedp,
              unsigned* __restrict__ survk, unsigned* __restrict__ cnts)
{
    const int lane = threadIdx.x & 63;
    const int wq = __builtin_amdgcn_readfirstlane(
        (int)((blockIdx.x * 256u + (unsigned)threadIdx.x) >> 6));  // query id
    const int b  = wq >> 13;
    const int qi = wq & (NPTS - 1);
    const float* base = pts + (size_t)b * (NPTS * 3);
    const unsigned* cs = cellStart + b * (NCELLS + 1);
    const float4* sp = sortedp + (size_t)b * NPTS;

    const float qx = base[qi * 3 + 0];   // wave-uniform scalar loads
    const float qy = base[qi * 3 + 1];
    const float qz = base[qi * 3 + 2];
    const float g2 = g2buf[wq];
    const float g  = sqrtf(g2);

    int ixlo = cidx(qx - g), ixhi = cidx(qx + g);
    int iylo = cidx(qy - g), iyhi = cidx(qy + g);
    int izlo = cidx(qz - g), izhi = cidx(qz + g);
    int nx = ixhi - ixlo + 1;
    int ny = iyhi - iylo + 1;
    int nyz = ny * (izhi - izlo + 1);
    const int lR  = (nyz >= 8) ? 3 : (nyz >= 4) ? 2 : (nyz >= 2) ? 1 : 0;
    const int R   = 1 << lR;
    const int lsl = 6 - lR;
    const unsigned SL = 64u >> lR;
    const unsigned slot = (unsigned)lane & (SL - 1u);
    unsigned cnt = 0;                          // wave-uniform by construction
    unsigned sbase = (unsigned)wq * SSTRIDE;
    #pragma unroll 1
    for (int r0 = 0; r0 < nyz; r0 += 64) {
        int r = r0 + lane;
        unsigned pk = 0;
        if (r < nyz) {
            int iz = izlo + r / ny;
            int iy = iylo + (r - (r / ny) * ny);
            int cb = (iz * NC + iy) * NC + ixlo;
            unsigned sB = cs[cb];
            pk = sB | ((cs[cb + nx] - sB) << 14);
        }
        int rmax = min(nyz - r0, 64);
        int gcount = (rmax + R - 1) >> lR;
        #pragma unroll 1
        for (int gg = 0; gg < gcount; ++gg) {
            unsigned pkm = __shfl(pk, (gg << lR) + (lane >> lsl), 64);
            unsigned sBm = pkm & 0x3FFFu;
            unsigned lm  = pkm >> 14;
            #pragma unroll 1
            for (unsigned st = slot; ; st += SL) {
                bool in = st < lm;
                if (!__any(in ? 1 : 0)) break;
                float4 c = sp[min(sBm + st, (unsigned)(NPTS - 1))];
                float dx = qx - c.x, dy = qy - c.y, dz = qz - c.z;
                float d2 = dx * dx + dy * dy + dz * dz;   // reference-form d2
                bool pass = in && (d2 < g2);
                unsigned long long m = __ballot(pass);
                if (pass) {
                    unsigned sw = min(cnt + mbcnt64(m), (unsigned)(SSTRIDE - 1));
                    survk[sbase + sw] = mkkey(d2, __float_as_uint(c.w));
                }
                cnt += (unsigned)__popcll(m);
            }
        }
    }
    if (lane == 0) cnts[wq] = cnt;
}

// Block = 256 threads, 32 queries; grid 1024. R8: selection ONLY -- writes
// top-16 GLOBAL POINT INDICES per (query,type) to idx16; the fp64 cov+eig3
// (measured ~60% of R7 select's wave stream, at 25% lane utilization x4
// redundant wave-streams) moves to eig_loss_kernel at full lane utilization.
__global__ void __launch_bounds__(256, 4)
select_kernel(const float* __restrict__ pts,
              const float* __restrict__ g2buf,
              const unsigned* __restrict__ survk_g,
              const unsigned* __restrict__ cnts_g,
              unsigned* __restrict__ idx16)
{
    __shared__ float4 pbuf4[PTCH];                 // 4 KB own patch
    __shared__ unsigned survl[NQ * SSTRIDE];       // 16.6 KB survivor keys
    __shared__ unsigned cnts[NQ];

    const int t = threadIdx.x;
    const int w = t >> 6;
    const int lane = t & 63;
    const int p = blockIdx.x;
    const int eighth = blockIdx.y;
    const int b = blockIdx.z;

    const float* base = pts + (size_t)b * (NPTS * 3);
    const int qbase = p * PTCH + eighth * NQ;
    const int qg0 = b * NPTS + qbase;              // block's first global query id

    // Stage own patch into padded LDS.
    {
        const float* src = base + p * (PTCH * 3);
        float* dst = (float*)pbuf4;
        #pragma unroll
        for (int s = 0; s < 3; ++s) {
            int f = t + s * 256;
            int j = f / 3;
            int c = f - 3 * j;
            dst[j * 4 + c] = src[f];
        }
    }
    // Stage survivors (fully coalesced rows) + counts.
    {
        const unsigned* src = survk_g + (size_t)qg0 * SSTRIDE;
        #pragma unroll 1
        for (int i = t; i < NQ * SSTRIDE; i += 256) survl[i] = src[i];
        if (t < NQ) cnts[t] = cnts_g[qg0 + t];
    }
    __syncthreads();

    // ---- 4 lanes per query ----
    const int qq = lane >> 2;            // query within half 0..15
    const int h = lane & 3;              // sub-lane
    const int myq = (w & 1) * 16 + qq;   // query 0..31
    float4 qv = pbuf4[eighth * NQ + myq];
    const float pqx = qv.x, pqy = qv.y, pqz = qv.z;

    if (w < 2) {
        // Global top-16: split survivor keys 4 ways, gated bubble, butterfly merge.
        unsigned gl[KNN];
        #pragma unroll
        for (int m = 0; m < KNN; ++m) gl[m] = 0xFFFFFFFFu;
        unsigned cnt = cnts[myq];
        bool valid = (cnt >= KNN) && (cnt <= SSTRIDE);
        if (valid) {
            unsigned share = (cnt + 3) >> 2;
            unsigned m0 = h * share;
            unsigned m1 = min(m0 + share, cnt);
            #pragma unroll 4
            for (unsigned m = m0; m < m1; ++m) {
                unsigned k = survl[myq * SSTRIDE + m];
                if (k < gl[KNN - 1]) insert16(k, gl);
            }
        }
        merge4(gl, lane);
        if (valid) {
            // margin check: all filtered-out points provably outside 16th bucket
            float g = g2buf[qg0 + myq];
            float upper = __uint_as_float((gl[KNN - 1] & 0xFFFFE000u) + 0x2000u);
            valid = (upper < g * 0.999f - 1e-5f);
        }
        if (__any((h == 0 && !valid) ? 1 : 0)) {
            if (h == 0 && !valid) {   // exact fallback (P ~ 1e-9/query)
                #pragma unroll
                for (int m = 0; m < KNN; ++m) gl[m] = 0xFFFFFFFFu;
                #pragma unroll 1
                for (int i = 0; i < NPTS; ++i) {
                    float cx = base[i * 3 + 0];
                    float cy = base[i * 3 + 1];
                    float cz = base[i * 3 + 2];
                    float dx = pqx - cx, dy = pqy - cy, dz = pqz - cz;
                    float d2 = dx * dx + dy * dy + dz * dz;
                    unsigned k = mkkey(d2, (unsigned)i);
                    if (k < gl[KNN - 1]) insert16(k, gl);
                }
            }
        }
        if (h == 0) {
            unsigned* dst = idx16 + (size_t)(qg0 + myq) * 32;   // type 0 = global
            #pragma unroll
            for (int m = 0; m < KNN; ++m) dst[m] = gl[m] & 0x1FFFu;
        }
    } else {
        // Patch kNN: 4 lanes x 64 patch points, gated bubble, butterfly merge.
        unsigned pl[KNN];
        #pragma unroll
        for (int m = 0; m < KNN; ++m) pl[m] = 0xFFFFFFFFu;
        const int j0 = h * 64;
        #pragma unroll 4
        for (int j = j0; j < j0 + 64; ++j) {
            float4 c = pbuf4[j];
            float dx = pqx - c.x, dy = pqy - c.y, dz = pqz - c.z;
            float d2 = dx * dx + dy * dy + dz * dz;
            unsigned k = mkkey(d2, (unsigned)j);
            if (k < pl[KNN - 1]) insert16(k, pl);
        }
        merge4(pl, lane);
        if (h == 0) {
            unsigned* dst = idx16 + (size_t)(qg0 + myq) * 32 + 16;  // type 1 = patch
            #pragma unroll
            for (int m = 0; m < KNN; ++m)
                dst[m] = (unsigned)(p * PTCH) + (pl[m] & 0x1FFFu);  // global point idx
        }
    }
}

// 1 thread per eig (65536 = 32768 queries x {global,patch}); full-lane fp64.
// Even/odd lanes hold (global,patch) of the same query -> shfl_xor(1) pairs
// them for the loss; block partial sums -> partials (fixed-order reduce after).
__global__ void __launch_bounds__(256)
eig_loss_kernel(const float* __restrict__ pts,
                const unsigned* __restrict__ idx16,
                double* __restrict__ partials)
{
    __shared__ double sln[4], slv[4];
    const int t = threadIdx.x;
    const int e = blockIdx.x * 256 + t;     // 0..65535
    const int qid = e >> 1;
    const int b = qid >> 13;
    const int qi = qid & (NPTS - 1);
    const float* base = pts + (size_t)b * (NPTS * 3);

    const double qxd = (double)base[qi * 3 + 0];
    const double qyd = (double)base[qi * 3 + 1];
    const double qzd = (double)base[qi * 3 + 2];

    const unsigned* L = idx16 + (size_t)qid * 32 + (e & 1) * 16;
    double c00 = 0, c11 = 0, c22 = 0, c01 = 0, c02 = 0, c12 = 0;
    #pragma unroll
    for (int m = 0; m < KNN; ++m) {
        int idx = (int)L[m];
        double dx = (double)base[idx * 3 + 0] - qxd;
        double dy = (double)base[idx * 3 + 1] - qyd;
        double dz = (double)base[idx * 3 + 2] - qzd;
        c00 += dx * dx; c11 += dy * dy; c22 += dz * dz;
        c01 += dx * dy; c02 += dx * dz; c12 += dy * dz;
    }
    double nx, ny, nz, lmin, lsum;
    eig3(c00, c11, c22, c01, c02, c12, nx, ny, nz, lmin, lsum);
    double sv = lmin / lsum;

    // partner (other type of same query) lives in the adjacent lane
    double onx = __shfl_xor(nx, 1, 64);
    double ony = __shfl_xor(ny, 1, 64);
    double onz = __shfl_xor(nz, 1, 64);
    double osv = __shfl_xor(sv, 1, 64);

    double ln = 0.0, lsv = 0.0;
    if ((e & 1) == 0) {          // even lane: own = global, partner = patch
        double dx = fabs(onx) - fabs(nx);
        double dy = fabs(ony) - fabs(ny);
        double dz = fabs(onz) - fabs(nz);
        ln  = sqrt(dx * dx + dy * dy + dz * dz);
        double ds = osv - sv;
        lsv = ds * ds;
    }
    #pragma unroll
    for (int o = 32; o > 0; o >>= 1) {
        ln  += __shfl_down(ln, o);
        lsv += __shfl_down(lsv, o);
    }
    const int w = t >> 6;
    if ((t & 63) == 0) { sln[w] = ln; slv[w] = lsv; }
    __syncthreads();
    if (t == 0) {
        partials[blockIdx.x * 2 + 0] = sln[0] + sln[1] + sln[2] + sln[3];
        partials[blockIdx.x * 2 + 1] = slv[0] + slv[1] + slv[2] + slv[3];
    }
}

// 1 block: deterministic fixed-order double sum of 256 partial pairs.
__global__ void __launch_bounds__(256)
reduce_kernel(const double* __restrict__ partials, float* __restrict__ out)
{
    __shared__ double sln[4], slv[4];
    const int t = threadIdx.x;
    double a = partials[t * 2 + 0];
    double c = partials[t * 2 + 1];
    #pragma unroll
    for (int o = 32; o > 0; o >>= 1) {
        a += __shfl_down(a, o);
        c += __shfl_down(c, o);
    }
    if ((t & 63) == 0) { sln[t >> 6] = a; slv[t >> 6] = c; }
    __syncthreads();
    if (t == 0) {
        const double inv = 1.0 / (double)(NBATCH * NPTS);
        out[0] = (float)((sln[0] + sln[1] + sln[2] + sln[3]) * inv);
        out[1] = (float)((slv[0] + slv[1] + slv[2] + slv[3]) * inv);
    }
}

// ---------------- legacy monolith (R5) — used only if workspace too small ----
__global__ void __launch_bounds__(256, 4)
spl_main(const float* __restrict__ pts, float* __restrict__ out,
         const unsigned* __restrict__ cellStart, const float4* __restrict__ sortedp)
{
    __shared__ float4 pbuf4[PTCH];
    __shared__ unsigned survk[NQ * SSTRIDE];
    __shared__ unsigned cnts[NQ];
    __shared__ float gbuf[NQ];
    __shared__ double xbuf[NQ * 4];
    __shared__ double rb[4];

    const int t = threadIdx.x;
    const int w = t >> 6;
    const int lane = t & 63;
    const int p = blockIdx.x;
    const int eighth = blockIdx.y;
    const int b = blockIdx.z;

    const float* base = pts + (size_t)b * (NPTS * 3);
    const int qbase = p * PTCH + eighth * NQ;
    const unsigned* cs = cellStart + b * (NCELLS + 1);
    const float4* sp = sortedp + (size_t)b * NPTS;

    {
        const float* src = base + p * (PTCH * 3);
        float* dst = (float*)pbuf4;
        #pragma unroll
        for (int s = 0; s < 3; ++s) {
            int f = t + s * 256;
            int j = f / 3;
            int c = f - 3 * j;
            dst[j * 4 + c] = src[f];
        }
    }
    if (t < NQ) {
        int qi = qbase + t;
        float x = base[qi * 3 + 0], y = base[qi * 3 + 1], z = base[qi * 3 + 2];
        float r = fmaxf(sqrtf(x * x + y * y + z * z), 0.01f);
        float lo = 0.f, hi = 12.f;
        #pragma unroll 1
        for (int it = 0; it < 16; ++it) {
            float mid = 0.5f * (lo + hi);
            if (lam_f(r, mid) < LAMBDA_T) lo = mid; else hi = mid;
        }
        gbuf[t] = hi * hi;
    }
    __syncthreads();

    #pragma unroll 1
    for (int u = 0; u < 8; ++u) {
        const int q = w * 8 + u;
        float4 qv = pbuf4[eighth * NQ + q];
        float qx = rfl(qv.x), qy = rfl(qv.y), qz = rfl(qv.z);
        float g2 = rfl(gbuf[q]);
        float g = sqrtf(g2);
        int ixlo = cidx(qx - g), ixhi = cidx(qx + g);
        int iylo = cidx(qy - g), iyhi = cidx(qy + g);
        int izlo = cidx(qz - g), izhi = cidx(qz + g);
        int nx = ixhi - ixlo + 1;
        int ny = iyhi - iylo + 1;
        int nyz = ny * (izhi - izlo + 1);
        const int lR  = (nyz >= 8) ? 3 : (nyz >= 4) ? 2 : (nyz >= 2) ? 1 : 0;
        const int R   = 1 << lR;
        const int lsl = 6 - lR;
        const unsigned SL = 64u >> lR;
        const unsigned slot = (unsigned)lane & (SL - 1u);
        unsigned cnt = 0;
        unsigned sbase = (unsigned)q * SSTRIDE;
        #pragma unroll 1
        for (int r0 = 0; r0 < nyz; r0 += 64) {
            int r = r0 + lane;
            unsigned pk = 0;
            if (r < nyz) {
                int iz = izlo + r / ny;
                int iy = iylo + (r - (r / ny) * ny);
                int cb = (iz * NC + iy) * NC + ixlo;
                unsigned sB = cs[cb];
                pk = sB | ((cs[cb + nx] - sB) << 14);
            }
            int rmax = min(nyz - r0, 64);
            int gcount = (rmax + R - 1) >> lR;
            #pragma unroll 1
            for (int gg = 0; gg < gcount; ++gg) {
                unsigned pkm = __shfl(pk, (gg << lR) + (lane >> lsl), 64);
                unsigned sBm = pkm & 0x3FFFu;
                unsigned lm  = pkm >> 14;
                #pragma unroll 1
                for (unsigned st = slot; ; st += SL) {
                    bool in = st < lm;
                    if (!__any(in ? 1 : 0)) break;
                    float4 c = sp[min(sBm + st, (unsigned)(NPTS - 1))];
                    float dx = qx - c.x, dy = qy - c.y, dz = qz - c.z;
                    float d2 = dx * dx + dy * dy + dz * dz;
                    bool pass = in && (d2 < g2);
                    unsigned long long m = __ballot(pass);
                    if (pass) {
                        unsigned sw = min(cnt + mbcnt64(m), (unsigned)(SSTRIDE - 1));
                        survk[sbase + sw] = mkkey(d2, __float_as_uint(c.w));
                    }
                    cnt += (unsigned)__popcll(m);
                }
            }
        }
        if (lane == 0) cnts[q] = cnt;
    }
    __syncthreads();

    const int qq = lane >> 2;
    const int h = lane & 3;
    const int myq = (w & 1) * 16 + qq;
    float4 qv = pbuf4[eighth * NQ + myq];
    const float pqx = qv.x, pqy = qv.y, pqz = qv.z;

    double ngx = 0, ngy = 0, ngz = 0, svg = 0;

    if (w < 2) {
        unsigned gl[KNN];
        #pragma unroll
        for (int m = 0; m < KNN; ++m) gl[m] = 0xFFFFFFFFu;
        unsigned cnt = cnts[myq];
        bool valid = (cnt >= KNN) && (cnt <= SSTRIDE);
        if (valid) {
            unsigned share = (cnt + 3) >> 2;
            unsigned m0 = h * share;
            unsigned m1 = min(m0 + share, cnt);
            #pragma unroll 1
            for (unsigned m = m0; m < m1; ++m) {
                unsigned k = survk[myq * SSTRIDE + m];
                if (k < gl[KNN - 1]) insert16(k, gl);
            }
        }
        merge4(gl, lane);
        if (valid) {
            float g = gbuf[myq];
            float upper = __uint_as_float((gl[KNN - 1] & 0xFFFFE000u) + 0x2000u);
            valid = (upper < g * 0.999f - 1e-5f);
        }
        if (__any((h == 0 && !valid) ? 1 : 0)) {
            if (h == 0 && !valid) {
                #pragma unroll
                for (int m = 0; m < KNN; ++m) gl[m] = 0xFFFFFFFFu;
                #pragma unroll 1
                for (int i = 0; i < NPTS; ++i) {
                    float cx = base[i * 3 + 0];
                    float cy = base[i * 3 + 1];
                    float cz = base[i * 3 + 2];
                    float dx = pqx - cx, dy = pqy - cy, dz = pqz - cz;
                    float d2 = dx * dx + dy * dy + dz * dz;
                    unsigned k = mkkey(d2, (unsigned)i);
                    if (k < gl[KNN - 1]) insert16(k, gl);
                }
            }
        }
        if (h == 0) {
            double c00 = 0, c11 = 0, c22 = 0, c01 = 0, c02 = 0, c12 = 0;
            const double qxd = pqx, qyd = pqy, qzd = pqz;
            #pragma unroll
            for (int m = 0; m < KNN; ++m) {
                int idx = (int)(gl[m] & 0x1FFFu);
                double dx = (double)base[idx * 3 + 0] - qxd;
                double dy = (double)base[idx * 3 + 1] - qyd;
                double dz = (double)base[idx * 3 + 2] - qzd;
                c00 += dx * dx; c11 += dy * dy; c22 += dz * dz;
                c01 += dx * dy; c02 += dx * dz; c12 += dy * dz;
            }
            double lmin, lsum;
            eig3(c00, c11, c22, c01, c02, c12, ngx, ngy, ngz, lmin, lsum);
            svg = lmin / lsum;
        }
    } else {
        unsigned pl[KNN];
        #pragma unroll
        for (int m = 0; m < KNN; ++m) pl[m] = 0xFFFFFFFFu;
        const int j0 = h * 64;
        #pragma unroll 1
        for (int j = j0; j < j0 + 64; ++j) {
            float4 c = pbuf4[j];
            float dx = pqx - c.x, dy = pqy - c.y, dz = pqz - c.z;
            float d2 = dx * dx + dy * dy + dz * dz;
            unsigned k = mkkey(d2, (unsigned)j);
            if (k < pl[KNN - 1]) insert16(k, pl);
        }
        merge4(pl, lane);
        if (h == 0) {
            double c00 = 0, c11 = 0, c22 = 0, c01 = 0, c02 = 0, c12 = 0;
            const double qxd = pqx, qyd = pqy, qzd = pqz;
            #pragma unroll
            for (int m = 0; m < KNN; ++m) {
                int idx = (int)(pl[m] & 0x1FFFu);
                float4 cpt = pbuf4[idx];
                double dx = (double)cpt.x - qxd;
                double dy = (double)cpt.y - qyd;
                double dz = (double)cpt.z - qzd;
                c00 += dx * dx; c11 += dy * dy; c22 += dz * dz;
                c01 += dx * dy; c02 += dx * dz; c12 += dy * dz;
            }
            double nx, ny, nz, lmin, lsum;
            eig3(c00, c11, c22, c01, c02, c12, nx, ny, nz, lmin, lsum);
            xbuf[myq * 4 + 0] = nx;
            xbuf[myq * 4 + 1] = ny;
            xbuf[myq * 4 + 2] = nz;
            xbuf[myq * 4 + 3] = lmin / lsum;
        }
    }
    __syncthreads();

    double ln = 0.0, lsv = 0.0;
    if (w < 2 && h == 0) {
        double npx = xbuf[myq * 4 + 0];
        double npy = xbuf[myq * 4 + 1];
        double npz = xbuf[myq * 4 + 2];
        double svp = xbuf[myq * 4 + 3];
        double dx = fabs(npx) - fabs(ngx);
        double dy = fabs(npy) - fabs(ngy);
        double dz = fabs(npz) - fabs(ngz);
        ln  = sqrt(dx * dx + dy * dy + dz * dz);
        double ds = svp - svg;
        lsv = ds * ds;
    }
    if (w < 2) {
        #pragma unroll
        for (int o = 32; o > 0; o >>= 1) {
            ln  += __shfl_down(ln, o);
            lsv += __shfl_down(lsv, o);
        }
        if (lane == 0) { rb[w * 2 + 0] = ln; rb[w * 2 + 1] = lsv; }
    }
    __syncthreads();
    if (t == 0) {
        const double inv = 1.0 / (double)(NBATCH * NPTS);
        atomicAdd(&out[0], (float)((rb[0] + rb[2]) * inv));
        atomicAdd(&out[1], (float)((rb[1] + rb[3]) * inv));
    }
}

extern "C" void kernel_launch(void* const* d_in, const int* in_sizes, int n_in,
                              void* d_out, int out_size, void* d_ws, size_t ws_size,
                              hipStream_t stream)
{
    const float* pts = (const float*)d_in[0];
    float* out = (float*)d_out;

    // workspace carve-up (16B-aligned):
    //   cellStart @ 0        : 4*4097*4      = 65552
    //   sorted    @ 65552    : 4*8192*16     = 524288   -> 589840
    //   g2buf     @ 589840   : 32768*4       = 131072   -> 720912
    //   cnts      @ 720912   : 32768*4       = 131072   -> 851984
    //   survk     @ 851984   : 32768*130*4   = 17039360 -> 17891344
    //   idx16     @ 17891344 : 32768*32*4    = 4194304  -> 22085648
    //   partials  @ 22085648 : 256*2*8       = 4096     -> 22089744 total
    unsigned char* ws = (unsigned char*)d_ws;
    unsigned* cellStart = (unsigned*)(ws);
    float4*   sorted    = (float4*)  (ws + 65552);
    float*    g2buf     = (float*)   (ws + 589840);
    unsigned* cnts      = (unsigned*)(ws + 720912);
    unsigned* survk     = (unsigned*)(ws + 851984);
    unsigned* idx16     = (unsigned*)(ws + 17891344);
    double*   partials  = (double*)  (ws + 22085648);

    hipLaunchKernelGGL(build_kernel, dim3(NBATCH), dim3(BT), 0, stream,
                       pts, out, cellStart, sorted);
    if (ws_size >= (size_t)22089744) {
        hipLaunchKernelGGL(gate_kernel, dim3(NBATCH * NPTS / 256), dim3(256), 0, stream,
                           pts, g2buf);
        hipLaunchKernelGGL(filter_kernel, dim3(NBATCH * NPTS / 4), dim3(256), 0, stream,
                           pts, g2buf, cellStart, sorted, survk, cnts);
        dim3 grid(NPATCH, 8, NBATCH);
        hipLaunchKernelGGL(select_kernel, grid, dim3(256), 0, stream,
                           pts, g2buf, survk, cnts, idx16);
        hipLaunchKernelGGL(eig_loss_kernel, dim3(NBATCH * NPTS * 2 / 256), dim3(256),
                           0, stream, pts, idx16, partials);
        hipLaunchKernelGGL(reduce_kernel, dim3(1), dim3(256), 0, stream,
                           partials, out);
    } else {
        dim3 grid(NPATCH, 8, NBATCH);
        hipLaunchKernelGGL(spl_main, grid, dim3(256), 0, stream,
                           pts, out, cellStart, sorted);
    }
}

// Round 9
// 151.428 us; speedup vs baseline: 1.0782x; 1.0370x over previous
//
#include <hip/hip_runtime.h>
#include <math.h>

#define KNN 16
#define NPTS 8192
#define PTCH 256
#define NPATCH 32
#define NBATCH 4
#define SSTRIDE 130      // survivor slots/query (mean 64, +8sigma)
#define LAMBDA_T 64.0f   // target E[survivors]/query

// spatial grid
#define NC 16
#define NCELLS (NC * NC * NC)
#define GMIN -4.2f
#define ICS 1.9047619f   // 1 / 0.525 ; NC*0.525 = 8.4 spans [-4.2, 4.2]

// E[#points within distance s of a query at radius r], N iid N(0,I3). fp32.
// Heuristic only: exactness guaranteed by margin check + fallback.
__device__ __forceinline__ float lam_f(float r, float s)
{
    const float C     = 0.063493636f;    // (2*pi)^{-3/2}
    const float SQ2PI = 2.5066283f;
    const float IS2   = 0.70710678f;
    float a = fabsf(r - s), b = r + s;
    float amr = a - r;
    float coefA = amr * amr + 2.f - s * s;
    float I = 2.f * __expf(-0.5f * b * b) - coefA * __expf(-0.5f * a * a)
            + r * SQ2PI * (erff(b * IS2) - erff(a * IS2));
    float M = C * (3.14159265f / r) * I;
    if (s > r) {
        float u = s - r;
        M += 12.566371f * C * (1.2533141f * erff(u * IS2) - u * __expf(-0.5f * u * u));
    }
    return (float)NPTS * M;
}

// ---------- fp64 cyclic Jacobi 3x3 (verified) ----------
__device__ __forceinline__ void jrot(double& app, double& aqq, double& apq,
                                     double& arp, double& arq,
                                     double& vp0, double& vq0,
                                     double& vp1, double& vq1,
                                     double& vp2, double& vq2)
{
    double g = apq;
    if (g == 0.0) return;
    double theta = (aqq - app) / (2.0 * g);
    double at = fabs(theta);
    double t = (at > 1.0e154) ? (0.5 / theta)
                              : (copysign(1.0, theta) / (at + sqrt(theta * theta + 1.0)));
    double c = 1.0 / sqrt(t * t + 1.0);
    double s = t * c;
    double tau = s / (1.0 + c);
    app -= t * g;
    aqq += t * g;
    apq = 0.0;
    double rp = arp, rq = arq;
    arp = rp - s * (rq + tau * rp);
    arq = rq + s * (rp - tau * rq);
    double p0 = vp0, q0 = vq0;
    vp0 = p0 - s * (q0 + tau * p0); vq0 = q0 + s * (p0 - tau * q0);
    double p1 = vp1, q1 = vq1;
    vp1 = p1 - s * (q1 + tau * p1); vq1 = q1 + s * (p1 - tau * q1);
    double p2 = vp2, q2 = vq2;
    vp2 = p2 - s * (q2 + tau * p2); vq2 = q2 + s * (p2 - tau * q2);
}

__device__ __forceinline__ void eig3(double a00, double a11, double a22,
                                     double a01, double a02, double a12,
                                     double& nx, double& ny, double& nz,
                                     double& lmin, double& lsum)
{
    double v00 = 1, v01 = 0, v02 = 0;
    double v10 = 0, v11 = 1, v12 = 0;
    double v20 = 0, v21 = 0, v22 = 1;
    double scale = fabs(a00) + fabs(a11) + fabs(a22) + fabs(a01) + fabs(a02) + fabs(a12);
    if (scale > 0.0) {
        for (int sweep = 0; sweep < 6; ++sweep) {
            double off = fabs(a01) + fabs(a02) + fabs(a12);
            if (off <= scale * 1e-15) break;
            jrot(a00, a11, a01, a02, a12, v00, v01, v10, v11, v20, v21);
            jrot(a00, a22, a02, a01, a12, v00, v02, v10, v12, v20, v22);
            jrot(a11, a22, a12, a01, a02, v01, v02, v11, v12, v21, v22);
        }
    }
    lsum = a00 + a11 + a22;
    lmin = a00; nx = v00; ny = v10; nz = v20;
    if (a11 < lmin) { lmin = a11; nx = v01; ny = v11; nz = v21; }
    if (a22 < lmin) { lmin = a22; nx = v02; ny = v12; nz = v22; }
}

// u32 key: (d2 float bits, low 13 mantissa bits cleared) | idx(13b). Ties -> lower idx.
__device__ __forceinline__ unsigned mkkey(float d2, unsigned idx) {
    return (__float_as_uint(d2) & 0xFFFFE000u) | idx;
}

// Caller guarantees key < L[15]. Sorted-ascending bubble (v_min/v_max pairs).
__device__ __forceinline__ void insert16(unsigned key, unsigned* L)
{
    L[KNN - 1] = key;
    #pragma unroll
    for (int m = KNN - 1; m >= 1; --m) {
        unsigned a = L[m - 1], b = L[m];
        L[m - 1] = min(a, b);
        L[m]     = max(a, b);
    }
}

// Snapshot-based butterfly merge of sorted 16-lists across lanes h = lane&3.
__device__ __forceinline__ void merge4(unsigned* L, int lane)
{
    #pragma unroll
    for (int step = 1; step <= 2; step <<= 1) {
        unsigned tmp[KNN];
        #pragma unroll
        for (int m = 0; m < KNN; ++m) tmp[m] = __shfl(L[m], lane ^ step, 64);
        for (int m = 0; m < KNN; ++m) {
            if (tmp[m] >= L[KNN - 1]) break;
            insert16(tmp[m], L);
        }
    }
}

__device__ __forceinline__ unsigned mbcnt64(unsigned long long m) {
    return __builtin_amdgcn_mbcnt_hi((unsigned)(m >> 32),
           __builtin_amdgcn_mbcnt_lo((unsigned)m, 0u));
}

// ---------- grid build ----------
__device__ __forceinline__ int cidx(float v) {
    int i = (int)floorf((v - GMIN) * ICS);
    return min(max(i, 0), NC - 1);
}
__device__ __forceinline__ int cellOf(float x, float y, float z) {
    return (cidx(z) * NC + cidx(y)) * NC + cidx(x);
}

// One block per batch: zero out + histogram + scan + scatter, all in LDS.
#define BT 1024
__global__ void __launch_bounds__(1024)
build_kernel(const float* __restrict__ pts, float* __restrict__ out,
             unsigned* __restrict__ cellStart, float4* __restrict__ sorted)
{
    __shared__ unsigned hist[NCELLS];     // 16 KB; reused as cellPos after scan
    __shared__ unsigned part[BT];         // 4 KB
    const int b = blockIdx.x;
    const int t = threadIdx.x;
    if (b == 0 && t == 0) { out[0] = 0.0f; out[1] = 0.0f; }
    for (int i = t; i < NCELLS; i += BT) hist[i] = 0u;
    __syncthreads();
    const float* base = pts + (size_t)b * (NPTS * 3);
    float px[8], py[8], pz[8];
    int pc[8];
    #pragma unroll
    for (int k = 0; k < 8; ++k) {
        int i = k * BT + t;
        px[k] = base[i * 3 + 0];
        py[k] = base[i * 3 + 1];
        pz[k] = base[i * 3 + 2];
        pc[k] = cellOf(px[k], py[k], pz[k]);
        atomicAdd(&hist[pc[k]], 1u);
    }
    __syncthreads();
    // scan: thread t owns cells t*4 .. t*4+3
    unsigned loc[4], s = 0;
    #pragma unroll
    for (int i = 0; i < 4; ++i) { loc[i] = s; s += hist[t * 4 + i]; }
    part[t] = s;
    __syncthreads();
    for (int o = 1; o < BT; o <<= 1) {
        unsigned u = (t >= o) ? part[t - o] : 0u;
        __syncthreads();
        part[t] += u;
        __syncthreads();
    }
    unsigned basex = part[t] - s;   // exclusive prefix of this thread's 4-cell chunk
    unsigned* csb = cellStart + b * (NCELLS + 1);
    #pragma unroll
    for (int i = 0; i < 4; ++i) {
        unsigned e = basex + loc[i];
        csb[t * 4 + i] = e;
        hist[t * 4 + i] = e;        // becomes running cell position
    }
    if (t == BT - 1) csb[NCELLS] = basex + s;   // == NPTS
    __syncthreads();
    float4* sb = sorted + (size_t)b * NPTS;
    #pragma unroll
    for (int k = 0; k < 8; ++k) {
        int i = k * BT + t;
        unsigned slot = atomicAdd(&hist[pc[k]], 1u);
        float4 v;
        v.x = px[k]; v.y = py[k]; v.z = pz[k]; v.w = __uint_as_float((unsigned)i);
        sb[slot] = v;
    }
}

// One THREAD per query: 32768 gate bisections fully SIMT-parallel.
__global__ void __launch_bounds__(256)
gate_kernel(const float* __restrict__ pts, float* __restrict__ g2buf)
{
    int q = blockIdx.x * 256 + threadIdx.x;     // 0..32767
    int b = q >> 13, i = q & (NPTS - 1);
    const float* pp = pts + (size_t)b * (NPTS * 3) + (size_t)i * 3;
    float x = pp[0], y = pp[1], z = pp[2];
    float r = fmaxf(sqrtf(x * x + y * y + z * z), 0.01f);
    float lo = 0.f, hi = 12.f;
    #pragma unroll 1
    for (int it = 0; it < 16; ++it) {
        float mid = 0.5f * (lo + hi);
        if (lam_f(r, mid) < LAMBDA_T) lo = mid; else hi = mid;
    }
    g2buf[q] = hi * hi;
}

// R9 fused filter+select: one WAVE per query. Stream candidates (row x slot),
// survivors -> LDS; then 32-step radix binary-search finds the exact 16th-
// smallest key P (keys distinct via idx tiebreak -> exactly 16 keys <= P);
// ballot-compact + 16-shfl rank sort emits the 16 global indices ascending --
// bit-identical set AND order vs the old insert16/merge4 path. Margin check
// on P + lane-0 exact fallback (P~1e-15) preserve exactness.
// Eliminates the survk global round-trip (9.4 MB write + 10.2 MB read) and
// the 35-50us select dispatch.
__global__ void __launch_bounds__(256)
fselect_kernel(const float* __restrict__ pts, const float* __restrict__ g2buf,
               const unsigned* __restrict__ cellStart,
               const float4* __restrict__ sortedp,
               unsigned* __restrict__ idx16)
{
    __shared__ unsigned survl[4 * SSTRIDE];   // 2 KB: 4 queries/block
    const int t = threadIdx.x;
    const int wv = t >> 6;
    const int lane = t & 63;
    const int wq = __builtin_amdgcn_readfirstlane(blockIdx.x * 4 + wv);  // query id
    const int b  = wq >> 13;
    const int qi = wq & (NPTS - 1);
    const float* base = pts + (size_t)b * (NPTS * 3);
    const unsigned* cs = cellStart + b * (NCELLS + 1);
    const float4* sp = sortedp + (size_t)b * NPTS;
    unsigned* sl = survl + wv * SSTRIDE;

    const float qx = base[qi * 3 + 0];   // wave-uniform scalar loads
    const float qy = base[qi * 3 + 1];
    const float qz = base[qi * 3 + 2];
    const float g2 = g2buf[wq];
    const float g  = sqrtf(g2);

    int ixlo = cidx(qx - g), ixhi = cidx(qx + g);
    int iylo = cidx(qy - g), iyhi = cidx(qy + g);
    int izlo = cidx(qz - g), izhi = cidx(qz + g);
    int nx = ixhi - ixlo + 1;
    int ny = iyhi - iylo + 1;
    int nyz = ny * (izhi - izlo + 1);
    const int lR  = (nyz >= 8) ? 3 : (nyz >= 4) ? 2 : (nyz >= 2) ? 1 : 0;
    const int R   = 1 << lR;
    const int lsl = 6 - lR;
    const unsigned SL = 64u >> lR;
    const unsigned slot = (unsigned)lane & (SL - 1u);
    unsigned cnt = 0;                          // wave-uniform by construction
    #pragma unroll 1
    for (int r0 = 0; r0 < nyz; r0 += 64) {
        int r = r0 + lane;
        unsigned pk = 0;
        if (r < nyz) {
            int iz = izlo + r / ny;
            int iy = iylo + (r - (r / ny) * ny);
            int cb = (iz * NC + iy) * NC + ixlo;
            unsigned sB = cs[cb];
            pk = sB | ((cs[cb + nx] - sB) << 14);
        }
        int rmax = min(nyz - r0, 64);
        int gcount = (rmax + R - 1) >> lR;
        #pragma unroll 1
        for (int gg = 0; gg < gcount; ++gg) {
            unsigned pkm = __shfl(pk, (gg << lR) + (lane >> lsl), 64);
            unsigned sBm = pkm & 0x3FFFu;
            unsigned lm  = pkm >> 14;
            #pragma unroll 1
            for (unsigned st = slot; ; st += SL) {
                bool in = st < lm;
                if (!__any(in ? 1 : 0)) break;
                float4 c = sp[min(sBm + st, (unsigned)(NPTS - 1))];
                float dx = qx - c.x, dy = qy - c.y, dz = qz - c.z;
                float d2 = dx * dx + dy * dy + dz * dz;   // reference-form d2
                bool pass = in && (d2 < g2);
                unsigned long long m = __ballot(pass);
                if (pass) {
                    unsigned sw = min(cnt + mbcnt64(m), (unsigned)(SSTRIDE - 1));
                    sl[sw] = mkkey(d2, __float_as_uint(c.w));
                }
                cnt += (unsigned)__popcll(m);
            }
        }
    }

    // ---- in-wave top-16 selection ----
    bool valid = (cnt >= KNN) && (cnt <= 128u);   // radix covers 128 keys (2/lane)
    if (valid) {
        unsigned k0 = (lane < (int)cnt)      ? sl[lane]      : 0xFFFFFFFFu;
        unsigned k1 = (lane + 64 < (int)cnt) ? sl[lane + 64] : 0xFFFFFFFFu;
        // radix binary search: P ends as the exact 16th-smallest key
        unsigned P = 0;
        #pragma unroll 1
        for (int bit = 31; bit >= 0; --bit) {
            unsigned mid = P | (1u << bit);
            unsigned c = (unsigned)__popcll(__ballot(k0 < mid))
                       + (unsigned)__popcll(__ballot(k1 < mid));
            if (c < 16u) P = mid;      // 16th smallest >= mid
        }
        // margin check: all filtered-out points provably outside 16th bucket
        float upper = __uint_as_float((P & 0xFFFFE000u) + 0x2000u);
        valid = (upper < g2 * 0.999f - 1e-5f);
        if (valid) {
            bool sel0 = (k0 <= P);
            bool sel1 = (k1 <= P);
            unsigned long long m0 = __ballot(sel0);
            unsigned long long m1 = __ballot(sel1);
            unsigned base1 = (unsigned)__popcll(m0);
            if (sel0) sl[mbcnt64(m0)] = k0;           // exactly 16 selected total
            if (sel1) sl[base1 + mbcnt64(m1)] = k1;
            unsigned myk = sl[lane & 15];             // lanes 0-15 meaningful
            unsigned rnk = 0;
            #pragma unroll
            for (int j = 0; j < 16; ++j) {
                unsigned kj = __shfl(myk, j, 64);
                rnk += (kj < myk) ? 1u : 0u;
            }
            if (lane < 16)
                idx16[(size_t)wq * 32 + rnk] = myk & 0x1FFFu;   // ascending order
        }
    }
    if (!valid && lane == 0) {       // exact fallback (P ~ 1e-15/query)
        unsigned gl[KNN];
        #pragma unroll
        for (int m = 0; m < KNN; ++m) gl[m] = 0xFFFFFFFFu;
        #pragma unroll 1
        for (int i = 0; i < NPTS; ++i) {
            float cx = base[i * 3 + 0];
            float cy = base[i * 3 + 1];
            float cz = base[i * 3 + 2];
            float dx = qx - cx, dy = qy - cy, dz = qz - cz;
            float d2 = dx * dx + dy * dy + dz * dz;
            unsigned k = mkkey(d2, (unsigned)i);
            if (k < gl[KNN - 1]) insert16(k, gl);
        }
        unsigned* dst = idx16 + (size_t)wq * 32;
        #pragma unroll
        for (int m = 0; m < KNN; ++m) dst[m] = gl[m] & 0x1FFFu;
    }
}

// Patch kNN: 64 queries/block (quarter patch), 4 lanes/query x 64 patch pts,
// gated bubble insert + butterfly merge4 (verbatim from old select_kernel).
__global__ void __launch_bounds__(256)
pselect_kernel(const float* __restrict__ pts, unsigned* __restrict__ idx16)
{
    __shared__ float4 pbuf4[PTCH];                 // 4 KB own patch
    const int t = threadIdx.x;
    const int w = t >> 6;
    const int lane = t & 63;
    const int p = blockIdx.x;
    const int quarter = blockIdx.y;
    const int b = blockIdx.z;
    const float* base = pts + (size_t)b * (NPTS * 3);

    {
        const float* src = base + p * (PTCH * 3);
        float* dst = (float*)pbuf4;
        #pragma unroll
        for (int s = 0; s < 3; ++s) {
            int f = t + s * 256;
            int j = f / 3;
            int c = f - 3 * j;
            dst[j * 4 + c] = src[f];
        }
    }
    __syncthreads();

    const int qq = lane >> 2;            // 0..15
    const int h = lane & 3;
    const int qlocal = quarter * 64 + w * 16 + qq;   // 0..255 within patch
    float4 qv = pbuf4[qlocal];
    const float pqx = qv.x, pqy = qv.y, pqz = qv.z;

    unsigned pl[KNN];
    #pragma unroll
    for (int m = 0; m < KNN; ++m) pl[m] = 0xFFFFFFFFu;
    const int j0 = h * 64;
    #pragma unroll 4
    for (int j = j0; j < j0 + 64; ++j) {
        float4 c = pbuf4[j];
        float dx = pqx - c.x, dy = pqy - c.y, dz = pqz - c.z;
        float d2 = dx * dx + dy * dy + dz * dz;
        unsigned k = mkkey(d2, (unsigned)j);
        if (k < pl[KNN - 1]) insert16(k, pl);
    }
    merge4(pl, lane);
    if (h == 0) {
        int qid = b * NPTS + p * PTCH + qlocal;
        unsigned* dst = idx16 + (size_t)qid * 32 + 16;   // type 1 = patch
        #pragma unroll
        for (int m = 0; m < KNN; ++m)
            dst[m] = (unsigned)(p * PTCH) + (pl[m] & 0x1FFFu);
    }
}

// 1 thread per eig (65536 = 32768 queries x {global,patch}); full-lane fp64.
__global__ void __launch_bounds__(256)
eig_loss_kernel(const float* __restrict__ pts,
                const unsigned* __restrict__ idx16,
                double* __restrict__ partials)
{
    __shared__ double sln[4], slv[4];
    const int t = threadIdx.x;
    const int e = blockIdx.x * 256 + t;     // 0..65535
    const int qid = e >> 1;
    const int b = qid >> 13;
    const int qi = qid & (NPTS - 1);
    const float* base = pts + (size_t)b * (NPTS * 3);

    const double qxd = (double)base[qi * 3 + 0];
    const double qyd = (double)base[qi * 3 + 1];
    const double qzd = (double)base[qi * 3 + 2];

    const unsigned* L = idx16 + (size_t)qid * 32 + (e & 1) * 16;
    double c00 = 0, c11 = 0, c22 = 0, c01 = 0, c02 = 0, c12 = 0;
    #pragma unroll
    for (int m = 0; m < KNN; ++m) {
        int idx = (int)L[m];
        double dx = (double)base[idx * 3 + 0] - qxd;
        double dy = (double)base[idx * 3 + 1] - qyd;
        double dz = (double)base[idx * 3 + 2] - qzd;
        c00 += dx * dx; c11 += dy * dy; c22 += dz * dz;
        c01 += dx * dy; c02 += dx * dz; c12 += dy * dz;
    }
    double nx, ny, nz, lmin, lsum;
    eig3(c00, c11, c22, c01, c02, c12, nx, ny, nz, lmin, lsum);
    double sv = lmin / lsum;

    double onx = __shfl_xor(nx, 1, 64);
    double ony = __shfl_xor(ny, 1, 64);
    double onz = __shfl_xor(nz, 1, 64);
    double osv = __shfl_xor(sv, 1, 64);

    double ln = 0.0, lsv = 0.0;
    if ((e & 1) == 0) {          // even lane: own = global, partner = patch
        double dx = fabs(onx) - fabs(nx);
        double dy = fabs(ony) - fabs(ny);
        double dz = fabs(onz) - fabs(nz);
        ln  = sqrt(dx * dx + dy * dy + dz * dz);
        double ds = osv - sv;
        lsv = ds * ds;
    }
    #pragma unroll
    for (int o = 32; o > 0; o >>= 1) {
        ln  += __shfl_down(ln, o);
        lsv += __shfl_down(lsv, o);
    }
    const int w = t >> 6;
    if ((t & 63) == 0) { sln[w] = ln; slv[w] = lsv; }
    __syncthreads();
    if (t == 0) {
        partials[blockIdx.x * 2 + 0] = sln[0] + sln[1] + sln[2] + sln[3];
        partials[blockIdx.x * 2 + 1] = slv[0] + slv[1] + slv[2] + slv[3];
    }
}

// 1 block: deterministic fixed-order double sum of 256 partial pairs.
__global__ void __launch_bounds__(256)
reduce_kernel(const double* __restrict__ partials, float* __restrict__ out)
{
    __shared__ double sln[4], slv[4];
    const int t = threadIdx.x;
    double a = partials[t * 2 + 0];
    double c = partials[t * 2 + 1];
    #pragma unroll
    for (int o = 32; o > 0; o >>= 1) {
        a += __shfl_down(a, o);
        c += __shfl_down(c, o);
    }
    if ((t & 63) == 0) { sln[t >> 6] = a; slv[t >> 6] = c; }
    __syncthreads();
    if (t == 0) {
        const double inv = 1.0 / (double)(NBATCH * NPTS);
        out[0] = (float)((sln[0] + sln[1] + sln[2] + sln[3]) * inv);
        out[1] = (float)((slv[0] + slv[1] + slv[2] + slv[3]) * inv);
    }
}

extern "C" void kernel_launch(void* const* d_in, const int* in_sizes, int n_in,
                              void* d_out, int out_size, void* d_ws, size_t ws_size,
                              hipStream_t stream)
{
    const float* pts = (const float*)d_in[0];
    float* out = (float*)d_out;

    // workspace carve-up (16B-aligned), ~4.9 MB total (prior rounds proved
    // ws_size >= 22 MB on this harness):
    //   cellStart @ 0       : 4*4097*4   = 65552
    //   sorted    @ 65552   : 4*8192*16  = 524288  -> 589840
    //   g2buf     @ 589840  : 32768*4    = 131072  -> 720912
    //   idx16     @ 720912  : 32768*32*4 = 4194304 -> 4915216
    //   partials  @ 4915216 : 256*2*8    = 4096    -> 4919312
    unsigned char* ws = (unsigned char*)d_ws;
    unsigned* cellStart = (unsigned*)(ws);
    float4*   sorted    = (float4*)  (ws + 65552);
    float*    g2buf     = (float*)   (ws + 589840);
    unsigned* idx16     = (unsigned*)(ws + 720912);
    double*   partials  = (double*)  (ws + 4915216);

    hipLaunchKernelGGL(build_kernel, dim3(NBATCH), dim3(BT), 0, stream,
                       pts, out, cellStart, sorted);
    hipLaunchKernelGGL(gate_kernel, dim3(NBATCH * NPTS / 256), dim3(256), 0, stream,
                       pts, g2buf);
    hipLaunchKernelGGL(fselect_kernel, dim3(NBATCH * NPTS / 4), dim3(256), 0, stream,
                       pts, g2buf, cellStart, sorted, idx16);
    hipLaunchKernelGGL(pselect_kernel, dim3(NPATCH, 4, NBATCH), dim3(256), 0, stream,
                       pts, idx16);
    hipLaunchKernelGGL(eig_loss_kernel, dim3(NBATCH * NPTS * 2 / 256), dim3(256),
                       0, stream, pts, idx16, partials);
    hipLaunchKernelGGL(reduce_kernel, dim3(1), dim3(256), 0, stream,
                       partials, out);
}